// Round 5
// baseline (268.788 us; speedup 1.0000x reference)
//
#include <hip/hip_runtime.h>
#include <hip/hip_fp16.h>

// DGCNN forward, fully fused: one workgroup per graph, TPB=768 (12 waves),
// 2 blocks/CU co-resident (24 waves/CU). f32 on the entire sort-key chain;
// h1/h2 archived to global f16 (conv features only); h3 read back from LDS f32.
//
// Occupancy rules learned R3-R9 (MI355X):
//  * NO launch_bounds min-waves / waves_per_eu hints -> allocator over-shrinks.
//  * 2 blocks co-schedule at VGPR<=64; keep VGPR under 64 (6 waves/SIMD at
//    TPB=768 needs VGPR<=85, so 64 is safe margin).
//  * R11: W1^T staged (stride 132) -> k-quad = one ds_read_b128; mid GEMMs
//    col-pair with paired W (stride 68). Bit-identical sums.
//  * R12: degree-sorted row->group assignment; csr pre-memset to QPAD;
//    dinv-scale merged into CSR phase; conv weights staged by idle threads;
//    cW2 stride 81.
//  * R13 FAILED: global-mirror dual-path agg -> VGPR 68, occupancy halved.
//  * R14 NEUTRAL: group-total balancing and fused rank didn't move the wall
//    -> agg is wave-starved LATENCY-bound (LDS port ~40%, VALU ~43%).
//  * R15: TPB 512 -> 768. 24 waves/CU (was 16): +50% latency hiding. Agg
//    groups 96: pass1 = 96 sorted pairs, 8 lightest singles to wave 11
//    (lightest pairs) -> wave wall ~13.5 iters (was ~21). Phase B re-tiled
//    24 islots x 4 rows x 2 passes; gemm_mid 48 slots x 4 rows (8 acc).

#define TPB   768
#define GRID  512
#define MG    200
#define EPG   6400
#define EE    (512 * EPG)

// ---- LDS layout (byte offsets). Total 75,488 B -> 2 blocks/CU (151/160 KiB) ----
#define OFF_BUFX 0        // f32[201*36] rows 0..200 (row 200 = zeros); later topv[30][100] + conv W
#define OFF_HCUR 28944    // f32[200*36] h of current layer; Phase A/B: staged W1^T [32][132]
#define OFF_CSR  57744    // u8[7200]    CSR (rows padded to x4 entries, pad -> 200)
#define OFF_ROFF 64944    // i32[201] row offsets (padded units)
#define OFF_CNT  65760    // i32[200] degree counts   \ scl f32[201] aliases CNT..CUR
#define OFF_CUR  66560    // i32[200] cursors         /
#define OFF_DINV 67360    // f32[200]
#define OFF_H4   68160    // f32[200] sort key
#define OFF_ORD  69760    // i32[30]
#define OFF_BIAS 69880    // f32[64]  double-buffered layer bias
#define OFF_RED  70136    // f32[16] (+8 pad)
#define OFF_WREG 70208    // f32[1088] W2/W3 paired stage [16][8][2][4] stride 68
#define OFF_HIST 74560    // i32[32]  quad-count histogram -> offsets
#define OFF_PERM 74688    // i32[200] degree-sorted row permutation (desc)
#define SMEM_BYTES 75488

#define QPAD 0xC8C8C8C8u   // 4x index 200 (zero row) - exact no-op quad

__device__ __forceinline__ float fast_tanh(float x) {
    const float e = __expf(2.0f * x);
    return 1.0f - 2.0f / (e + 1.0f);
}

__global__ __launch_bounds__(TPB)
void dgcnn_kernel(
    const float* __restrict__ x,
    const int*   __restrict__ ei,
    const float* __restrict__ W1, const float* __restrict__ b1,
    const float* __restrict__ W2, const float* __restrict__ b2,
    const float* __restrict__ W3, const float* __restrict__ b3,
    const float* __restrict__ W4, const float* __restrict__ b4,
    const float* __restrict__ cW1, const float* __restrict__ cb1,
    const float* __restrict__ cW2, const float* __restrict__ cb2,
    const float* __restrict__ lW1, const float* __restrict__ lb1,
    const float* __restrict__ lW2, const float* __restrict__ lb2,
    __half* __restrict__ arch,     // [512][200][64] f16 archive of h1|h2
    float* __restrict__ out)
{
    extern __shared__ unsigned char smem[];
    float* bufX = (float*)(smem + OFF_BUFX);
    float* hcur = (float*)(smem + OFF_HCUR);
    unsigned char* csr = (unsigned char*)(smem + OFF_CSR);
    int*   roff = (int*)(smem + OFF_ROFF);
    int*   cnt  = (int*)(smem + OFF_CNT);
    int*   cur  = (int*)(smem + OFF_CUR);
    float* dinv = (float*)(smem + OFF_DINV);
    float* h4k  = (float*)(smem + OFF_H4);
    int*   ord  = (int*)(smem + OFF_ORD);
    float* bias = (float*)(smem + OFF_BIAS);
    float* red  = (float*)(smem + OFF_RED);
    float* wreg = (float*)(smem + OFF_WREG);
    int*   hist = (int*)(smem + OFF_HIST);
    int*   perm = (int*)(smem + OFF_PERM);

    const int g = blockIdx.x;
    const int t = threadIdx.x;
    const int gbase = g * MG;
    const float* xg   = x + (size_t)gbase * 128;
    const int*   srcp = ei + (size_t)g * EPG;
    const int*   dstp = ei + (size_t)EE + (size_t)g * EPG;

    // ---------------- Phase A: stage W1^T -> hcur [32][132] (stride 132 == 4 mod 32),
    // csr memset to QPAD (kills pad-fill phase), bias, zeros, hist=0. ----
    for (int idx = t; idx < 4096; idx += TPB)
        hcur[(idx & 31) * 132 + (idx >> 5)] = W1[idx];
    for (int idx = t; idx < 1800; idx += TPB)
        ((unsigned*)csr)[idx] = QPAD;
    if (t < 32) bias[t] = b1[t];
    if (t < MG) cnt[t] = 0;
    if (t >= 480 && t < 512) hist[t - 480] = 0;
    if (t >= 256 && t < 292) bufX[200 * 36 + (t - 256)] = 0.f;   // zero row 200
    __syncthreads();

    const int f32lane = t & 31;   // feature (output col) 0..31
    const int islot   = t >> 5;   // row slot 0..23

    // ---------------- Phase B: edge in-degree count (int4) + L1 GEMM, one phase ----------
    {
        const int4* d4p = (const int4*)dstp;
        for (int e4 = t; e4 < EPG / 4; e4 += TPB) {
            const int4 d4 = d4p[e4];
            atomicAdd(&cnt[d4.x - gbase], 1);
            atomicAdd(&cnt[d4.y - gbase], 1);
            atomicAdd(&cnt[d4.z - gbase], 1);
            atomicAdd(&cnt[d4.w - gbase], 1);
        }
    }
    {
        const int f = f32lane;
        const float* wt = hcur + f * 132;      // column f of W1, k-major
        const float4* xv = (const float4*)xg;
        #pragma unroll
        for (int p = 0; p < 2; ++p) {
            const int r0 = islot + 96 * p;     // rows r0, r0+24, r0+48, r0+72
            float a0 = 0.f, a1 = 0.f, a2 = 0.f, a3 = 0.f;
            #pragma unroll 2
            for (int k4 = 0; k4 < 32; ++k4) {
                const float4 w = *(const float4*)(wt + 4 * k4);
                float4 v;
                v = xv[(r0      ) * 32 + k4]; a0 += v.x*w.x + v.y*w.y + v.z*w.z + v.w*w.w;
                v = xv[(r0 + 24 ) * 32 + k4]; a1 += v.x*w.x + v.y*w.y + v.z*w.z + v.w*w.w;
                v = xv[(r0 + 48 ) * 32 + k4]; a2 += v.x*w.x + v.y*w.y + v.z*w.z + v.w*w.w;
                v = xv[(r0 + 72 ) * 32 + k4]; a3 += v.x*w.x + v.y*w.y + v.z*w.z + v.w*w.w;
            }
            bufX[(r0      ) * 36 + f] = a0;
            bufX[(r0 + 24 ) * 36 + f] = a1;
            bufX[(r0 + 48 ) * 36 + f] = a2;
            bufX[(r0 + 72 ) * 36 + f] = a3;
        }
        if (islot < 8) {   // rows 192..199
            const int r = 192 + islot;
            float a0 = 0.f;
            #pragma unroll 2
            for (int k4 = 0; k4 < 32; ++k4) {
                const float4 w = *(const float4*)(wt + 4 * k4);
                const float4 v = xv[r * 32 + k4];
                a0 += v.x*w.x + v.y*w.y + v.z*w.z + v.w*w.w;
            }
            bufX[r * 36 + f] = a0;
        }
    }
    __syncthreads();

    // ---------------- Phase C: dinv + hist build + prefix scan over PADDED row lengths ----
    if (t >= 256 && t < 256 + MG) {
        const int i = t - 256;
        const int c = cnt[i];
        dinv[i] = 1.0f / sqrtf((float)(c + 1));
        int qc = (c + 4) >> 2;                 // padded quad count
        if (qc > 31) qc = 31;
        atomicAdd(&hist[31 - qc], 1);          // descending order
    }
    if (t < 64) {
        if (t == 0) roff[0] = 0;
        int carry = 0;
        #pragma unroll
        for (int c = 0; c < 4; ++c) {
            const int i = c * 64 + t;
            int v = (i < MG) ? ((cnt[i] + 4) & ~3) : 0;   // self-loop +1, pad to x4
            #pragma unroll
            for (int off = 1; off < 64; off <<= 1) {
                int u = __shfl_up(v, off);
                if (t >= (int)off) v += u;
            }
            if (i < MG) roff[i + 1] = carry + v;
            carry += __shfl(v, 63);
        }
    }
    __syncthreads();

    // ---------------- Phase D: self-loop entry + cursors + hist exclusive prefix ----------
    if (t < MG) {
        int p = roff[t];
        csr[p] = (unsigned char)t;
        cur[t] = p + 1;
    }
    if (t < 32) {
        const int own = hist[t];
        int v = own;
        #pragma unroll
        for (int off = 1; off < 32; off <<= 1) {
            int u = __shfl_up(v, off);
            if (t >= off) v += u;
        }
        hist[t] = v - own;   // exclusive offsets
    }
    __syncthreads();

    // ---------------- Phase E: CSR placement + dinv-scale bufX + perm scatter ------------
    {
        const int4* s4p = (const int4*)srcp;
        const int4* d4p = (const int4*)dstp;
        for (int e4 = t; e4 < EPG / 4; e4 += TPB) {
            const int4 s4 = s4p[e4];
            const int4 d4 = d4p[e4];
            int p;
            p = atomicAdd(&cur[d4.x - gbase], 1); csr[p] = (unsigned char)(s4.x - gbase);
            p = atomicAdd(&cur[d4.y - gbase], 1); csr[p] = (unsigned char)(s4.y - gbase);
            p = atomicAdd(&cur[d4.z - gbase], 1); csr[p] = (unsigned char)(s4.z - gbase);
            p = atomicAdd(&cur[d4.w - gbase], 1); csr[p] = (unsigned char)(s4.w - gbase);
        }
    }
    for (int r = islot; r < MG; r += 24) {
        bufX[r * 36 + f32lane] *= dinv[r];
    }
    if (t < MG) {
        int qc = (cnt[t] + 4) >> 2;
        if (qc > 31) qc = 31;
        const int pos = atomicAdd(&hist[31 - qc], 1);
        perm[pos] = t;   // perm: rows sorted by quad count, descending
    }
    __syncthreads();

    // agg: hcur[d][f] = tanh(dinv[d]*sum_{p} bufX[csr[p]][f] + bias[bb+f]);
    // 96 groups of 8 lanes. Pass 1: sorted-adjacent pairs (ranks 0..191).
    // Pass 2: 8 lightest singles (ranks 192..199) on wave 11 (lightest pairs)
    // -> balanced wave walls, no intra-wave divergence.
    auto agg_layer = [&](int archOff, int bb) {
        const int f4  = (t & 7) << 2;
        const int dsl = t >> 3;   // 0..95

        auto finish = [&](int d, float a0, float a1, float a2, float a3) {
            const float dv = dinv[d];
            const float o0 = fast_tanh(dv * a0 + bias[bb + f4 + 0]);
            const float o1 = fast_tanh(dv * a1 + bias[bb + f4 + 1]);
            const float o2 = fast_tanh(dv * a2 + bias[bb + f4 + 2]);
            const float o3 = fast_tanh(dv * a3 + bias[bb + f4 + 3]);
            *(float4*)(hcur + d * 36 + f4) = make_float4(o0, o1, o2, o3);
            if (archOff >= 0) {
                const __half2 p01 = __floats2half2_rn(o0, o1);
                const __half2 p23 = __floats2half2_rn(o2, o3);
                __half2* dst = (__half2*)(arch + (size_t)(gbase + d) * 64 + archOff + f4);
                dst[0] = p01;
                dst[1] = p23;
            }
        };

        auto pair_rows = [&](int da, int db) {
            const int p1a = roff[da + 1], p1b = roff[db + 1];
            int pa = roff[da], pb = roff[db];
            const int na = (p1a - pa) >> 2, nb = (p1b - pb) >> 2;
            const int iters = na > nb ? na : nb;
            unsigned qa = *(const unsigned*)(csr + pa);
            unsigned qb = *(const unsigned*)(csr + pb);
            float a0=0.f,a1=0.f,a2=0.f,a3=0.f, c0=0.f,c1=0.f,c2=0.f,c3=0.f;
            for (int i = 0; i < iters; ++i) {
                pa += 4; pb += 4;
                const unsigned qa_n = (pa < p1a) ? *(const unsigned*)(csr + pa) : QPAD;
                const unsigned qb_n = (pb < p1b) ? *(const unsigned*)(csr + pb) : QPAD;
                float4 v;
                v = *(const float4*)(bufX + (qa & 255u) * 36 + f4);         a0+=v.x; a1+=v.y; a2+=v.z; a3+=v.w;
                v = *(const float4*)(bufX + ((qa >> 8) & 255u) * 36 + f4);  a0+=v.x; a1+=v.y; a2+=v.z; a3+=v.w;
                v = *(const float4*)(bufX + ((qa >> 16) & 255u) * 36 + f4); a0+=v.x; a1+=v.y; a2+=v.z; a3+=v.w;
                v = *(const float4*)(bufX + (qa >> 24) * 36 + f4);          a0+=v.x; a1+=v.y; a2+=v.z; a3+=v.w;
                v = *(const float4*)(bufX + (qb & 255u) * 36 + f4);         c0+=v.x; c1+=v.y; c2+=v.z; c3+=v.w;
                v = *(const float4*)(bufX + ((qb >> 8) & 255u) * 36 + f4);  c0+=v.x; c1+=v.y; c2+=v.z; c3+=v.w;
                v = *(const float4*)(bufX + ((qb >> 16) & 255u) * 36 + f4); c0+=v.x; c1+=v.y; c2+=v.z; c3+=v.w;
                v = *(const float4*)(bufX + (qb >> 24) * 36 + f4);          c0+=v.x; c1+=v.y; c2+=v.z; c3+=v.w;
                qa = qa_n; qb = qb_n;
            }
            finish(da, a0, a1, a2, a3);
            finish(db, c0, c1, c2, c3);
        };

        auto one_row = [&](int d) {
            const int p1 = roff[d + 1];
            int p = roff[d];
            const int iters = (p1 - p) >> 2;
            unsigned q = *(const unsigned*)(csr + p);
            float a0=0.f,a1=0.f,a2=0.f,a3=0.f;
            for (int i = 0; i < iters; ++i) {
                p += 4;
                const unsigned q_n = (p < p1) ? *(const unsigned*)(csr + p) : QPAD;
                float4 v;
                v = *(const float4*)(bufX + (q & 255u) * 36 + f4);         a0+=v.x; a1+=v.y; a2+=v.z; a3+=v.w;
                v = *(const float4*)(bufX + ((q >> 8) & 255u) * 36 + f4);  a0+=v.x; a1+=v.y; a2+=v.z; a3+=v.w;
                v = *(const float4*)(bufX + ((q >> 16) & 255u) * 36 + f4); a0+=v.x; a1+=v.y; a2+=v.z; a3+=v.w;
                v = *(const float4*)(bufX + (q >> 24) * 36 + f4);          a0+=v.x; a1+=v.y; a2+=v.z; a3+=v.w;
                q = q_n;
            }
            finish(d, a0, a1, a2, a3);
        };

        // Pass 1: group g takes sorted pair (perm[2g], perm[2g+1]), g = 0..95.
        // Pass 2: groups 88..95 (wave 11, lightest pairs) take singles
        // perm[104+dsl] = ranks 192..199 (lightest rows). Coverage exact.
        pair_rows(perm[2 * dsl], perm[2 * dsl + 1]);
        if (dsl >= 88) one_row(perm[104 + dsl]);
    };

    auto gemm_mid = [&](const float* __restrict__ src) {
        // bufX = (src[200x32] @ W[32x32]) scaled by dinv[row]; W staged paired in
        // wreg: [f2][k4][c][4] stride 68 (== 4 mod 32, 2-way banks). Col-pair x
        // 4-row mapping (48 slots): each src b128 feeds 8 FMAs.
        const int f2 = t & 15;    // column pair: cols 2*f2, 2*f2+1
        const int sl = t >> 4;    // row slot 0..47
        const float* wp = wreg + f2 * 68;
        {
            float a0A=0.f,a1A=0.f,a2A=0.f,a3A=0.f;
            float a0B=0.f,a1B=0.f,a2B=0.f,a3B=0.f;
            #pragma unroll 2
            for (int k4 = 0; k4 < 8; ++k4) {
                const float4 wA = *(const float4*)(wp + k4 * 8);
                const float4 wB = *(const float4*)(wp + k4 * 8 + 4);
                float4 v;
                v = *(const float4*)(src + (sl       ) * 36 + 4 * k4);
                a0A += v.x*wA.x + v.y*wA.y + v.z*wA.z + v.w*wA.w;
                a0B += v.x*wB.x + v.y*wB.y + v.z*wB.z + v.w*wB.w;
                v = *(const float4*)(src + (sl + 48  ) * 36 + 4 * k4);
                a1A += v.x*wA.x + v.y*wA.y + v.z*wA.z + v.w*wA.w;
                a1B += v.x*wB.x + v.y*wB.y + v.z*wB.z + v.w*wB.w;
                v = *(const float4*)(src + (sl + 96  ) * 36 + 4 * k4);
                a2A += v.x*wA.x + v.y*wA.y + v.z*wA.z + v.w*wA.w;
                a2B += v.x*wB.x + v.y*wB.y + v.z*wB.z + v.w*wB.w;
                v = *(const float4*)(src + (sl + 144 ) * 36 + 4 * k4);
                a3A += v.x*wA.x + v.y*wA.y + v.z*wA.z + v.w*wA.w;
                a3B += v.x*wB.x + v.y*wB.y + v.z*wB.z + v.w*wB.w;
            }
            const int c0 = 2 * f2;
            *(float2*)(bufX + (sl       ) * 36 + c0) = make_float2(dinv[sl      ] * a0A, dinv[sl      ] * a0B);
            *(float2*)(bufX + (sl + 48  ) * 36 + c0) = make_float2(dinv[sl + 48 ] * a1A, dinv[sl + 48 ] * a1B);
            *(float2*)(bufX + (sl + 96  ) * 36 + c0) = make_float2(dinv[sl + 96 ] * a2A, dinv[sl + 96 ] * a2B);
            *(float2*)(bufX + (sl + 144 ) * 36 + c0) = make_float2(dinv[sl + 144] * a3A, dinv[sl + 144] * a3B);
        }
        if (sl < 8) {   // rows 192..199
            const int r = 192 + sl;
            float aA = 0.f, aB = 0.f;
            #pragma unroll 2
            for (int k4 = 0; k4 < 8; ++k4) {
                const float4 wA = *(const float4*)(wp + k4 * 8);
                const float4 wB = *(const float4*)(wp + k4 * 8 + 4);
                const float4 v = *(const float4*)(src + r * 36 + 4 * k4);
                aA += v.x*wA.x + v.y*wA.y + v.z*wA.z + v.w*wA.w;
                aB += v.x*wB.x + v.y*wB.y + v.z*wB.z + v.w*wB.w;
            }
            *(float2*)(bufX + r * 36 + 2 * f2) = make_float2(dinv[r] * aA, dinv[r] * aB);
        }
    };

    // paired-W staging: wreg[f2*68 + k4*8 + c*4 + j] = W[(4k4+j)*32 + 2f2+c]
    auto stage_w_paired = [&](const float* __restrict__ W) {
        for (int idx = t; idx < 1024; idx += TPB) {
            const int k = idx >> 5, f = idx & 31;
            wreg[(f >> 1) * 68 + (k >> 2) * 8 + ((f & 1) << 2) + (k & 3)] = W[idx];
        }
    };

    // ---------------- Layer 1 agg (+ stage W2/b2 in-phase, bias double-buffer) --------
    agg_layer(0, 0);    // h1 -> arch[:,0:32)
    stage_w_paired(W2);
    if (t < 32) bias[32 + t] = b2[t];
    __syncthreads();

    // ---------------- Layer 2 ----------------
    gemm_mid(hcur);
    __syncthreads();
    agg_layer(32, 32);  // h2 -> arch[:,32:64)
    stage_w_paired(W3);
    if (t < 32) bias[t] = b3[t];
    __syncthreads();

    // ---------------- Layer 3 ----------------
    gemm_mid(hcur);
    __syncthreads();
    agg_layer(-1, 0);   // h3 stays in hcur (f32), not archived
    __syncthreads();

    // conv weight staging targets (bufX dead after agg3 barrier)
    float* topv = bufX;           // [30][100] = 3000 floats
    float* cw   = bufX + 3008;    // cW1: [0,1552)  cW2 stride-81: [1552,5695); ends 7151 <= 7236

    // ---------------- Layer 4 (Fout=1): scl = dinv * (h3 @ W4); scl[200]=0 ----------------
    // Idle threads 256..767 stage cW1; threads 208..255 stage conv biases.
    float* scl = (float*)(smem + OFF_CNT);   // 400 floats available (cnt+cur dead)
    if (t < MG) {
        float a = 0.f;
        #pragma unroll 8
        for (int k = 0; k < 32; ++k) a += hcur[t * 36 + k] * W4[k];
        scl[t] = dinv[t] * a;
    }
    if (t == 200) scl[200] = 0.f;
    if (t >= 256) {
        for (int idx = t - 256; idx < 1552; idx += TPB - 256) cw[idx] = cW1[idx];
    } else if (t >= 208 && t < 224) {
        bias[t - 208] = cb1[t - 208];
    } else if (t >= 224 && t < 256) {
        bias[16 + (t - 224)] = cb2[t - 224];
    }
    __syncthreads();
    // h4k gather; idle threads stage cW2 at stride 81 (odd -> no bank aliasing in conv2)
    if (t < MG) {
        const int p0 = roff[t], p1 = roff[t + 1];
        float s = 0.f;
        for (int p = p0; p < p1; p += 4) {
            const unsigned q = *(const unsigned*)(csr + p);
            s += scl[q & 255u] + scl[(q >> 8) & 255u]
               + scl[(q >> 16) & 255u] + scl[q >> 24];
        }
        h4k[t] = fast_tanh(dinv[t] * s + b4[0]);
    }
    if (t >= 256) {
        for (int idx = t - 256; idx < 2560; idx += TPB - 256) {
            const int o = idx / 80, r = idx - o * 80;
            cw[1552 + o * 81 + r] = cW2[idx];
        }
    }
    __syncthreads();

    // ---------------- SortPool: fused exact stable rank + ord scatter ----------------
    // (desc value, asc index). Each of 200 threads ranks itself over all 200
    // (same-address LDS reads broadcast -> free); scatter ord directly.
    if (t < MG) {
        const float vi = h4k[t];
        int r = 0;
        for (int j = 0; j < MG; ++j) {
            const float vj = h4k[j];
            r += (vj > vi || (vj == vi && j < t)) ? 1 : 0;
        }
        if (r < 30) ord[r] = t;
    }
    __syncthreads();

    // ---------------- Gather top-30 features ----------
    for (int idx = t; idx < 2910; idx += TPB) {   // 30*97 grid-stride
        const int kk = idx / 97;
        const int ff = idx - kk * 97;
        const int nd = ord[kk];
        float v;
        if      (ff < 64) v = __half2float(arch[(size_t)(gbase + nd) * 64 + ff]);
        else if (ff < 96) v = hcur[nd * 36 + (ff - 64)];   // h3, f32
        else              v = h4k[nd];
        topv[kk * 100 + ff] = v;
    }
    __syncthreads();

    // conv scratch in hcur (dead after gather barrier)
    float* c1p2 = hcur;           // [16][30]
    float* c1pl = hcur + 480;     // [16][16]
    float* flat = hcur + 736;     // [352]
    float* hlin = hcur + 1088;    // [128]

    // ---------------- Conv1 (97->16 per slot) + ReLU ----------------
    if (t < 480) {
        const int o  = t & 15;
        const int tt = t >> 4;
        float a = bias[o];
        const float* wrow = cw + o * 97;
        const float* trow = topv + tt * 100;
        #pragma unroll 4
        for (int f = 0; f < 97; ++f) a += wrow[f] * trow[f];
        c1p2[o * 30 + tt] = fmaxf(a, 0.f);
    }
    __syncthreads();

    // ---------------- MaxPool1d(2,2): 30 -> 15 ----------------
    if (t < 240) {
        const int o  = t & 15;
        const int tp = t >> 4;
        c1pl[o * 16 + tp] = fmaxf(c1p2[o * 30 + 2 * tp], c1p2[o * 30 + 2 * tp + 1]);
    }
    __syncthreads();

    // ---------------- Conv2 (16->32, k=5) + ReLU -> flat; init hlin ----------------
    if (t < 352) {
        const int o  = t & 31;
        const int tt = t >> 5;
        float a = bias[16 + o];
        const float* w2r = cw + 1552 + o * 81;
        #pragma unroll
        for (int i2 = 0; i2 < 16; ++i2) {
            #pragma unroll
            for (int kk = 0; kk < 5; ++kk)
                a += w2r[i2 * 5 + kk] * c1pl[i2 * 16 + tt + kk];
        }
        flat[o * 11 + tt] = fmaxf(a, 0.f);
    } else if (t >= 352 && t < 480) {
        hlin[t - 352] = lb1[t - 352];
    }
    __syncthreads();

    // ---------------- Linear 352->128 (split-K over 4 groups of 88) ----------------
    if (t < 512) {
        const int f  = t & 127;
        const int kc = t >> 7;   // 0..3
        float a = 0.f;
        const int k0 = kc * 88;
        #pragma unroll 4
        for (int kk = k0; kk < k0 + 88; ++kk) a += flat[kk] * lW1[kk * 128 + f];
        atomicAdd(&hlin[f], a);
    }
    __syncthreads();

    // ---------------- ReLU -> Linear 128->1 -> sigmoid ----------------
    if (t < 128) {
        float p = fmaxf(hlin[t], 0.f) * lW2[t];
        #pragma unroll
        for (int off = 32; off > 0; off >>= 1) p += __shfl_down(p, off);
        if ((t & 63) == 0) red[t >> 6] = p;
    }
    __syncthreads();
    if (t == 0) {
        const float z = red[0] + red[1] + lb2[0];
        out[g] = 1.f / (1.f + expf(-z));
    }
}

extern "C" void kernel_launch(void* const* d_in, const int* in_sizes, int n_in,
                              void* d_out, int out_size, void* d_ws, size_t ws_size,
                              hipStream_t stream) {
    (void)in_sizes; (void)n_in; (void)out_size; (void)ws_size;
    const float* x   = (const float*)d_in[0];
    const int*   ei  = (const int*)d_in[1];
    const float* W1  = (const float*)d_in[3];  const float* b1  = (const float*)d_in[4];
    const float* W2  = (const float*)d_in[5];  const float* b2  = (const float*)d_in[6];
    const float* W3  = (const float*)d_in[7];  const float* b3  = (const float*)d_in[8];
    const float* W4  = (const float*)d_in[9];  const float* b4  = (const float*)d_in[10];
    const float* cW1 = (const float*)d_in[11]; const float* cb1 = (const float*)d_in[12];
    const float* cW2 = (const float*)d_in[13]; const float* cb2 = (const float*)d_in[14];
    const float* lW1 = (const float*)d_in[15]; const float* lb1 = (const float*)d_in[16];
    const float* lW2 = (const float*)d_in[17]; const float* lb2 = (const float*)d_in[18];
    float* out = (float*)d_out;
    __half* arch = (__half*)d_ws;   // needs 512*200*64*2 = 13.1 MB

    hipFuncSetAttribute((const void*)dgcnn_kernel,
                        hipFuncAttributeMaxDynamicSharedMemorySize, SMEM_BYTES);

    dgcnn_kernel<<<GRID, TPB, SMEM_BYTES, stream>>>(
        x, ei, W1, b1, W2, b2, W3, b3, W4, b4,
        cW1, cb1, cW2, cb2, lW1, lb1, lW2, lb2, arch, out);
}

// Round 6
// 267.699 us; speedup vs baseline: 1.0041x; 1.0041x over previous
//
#include <hip/hip_runtime.h>
#include <hip/hip_fp16.h>

// DGCNN forward, fully fused: one workgroup per graph, TPB=640 (10 waves),
// goal: 2 blocks/CU co-resident (20 waves/CU). f32 on the entire sort-key
// chain; h1/h2 archived to global f16; h3 read back from LDS f32.
//
// Occupancy rules learned R3-R15 (MI355X):
//  * NO launch_bounds min-waves / waves_per_eu hints -> allocator over-shrinks.
//  * 2 blocks co-schedule at VGPR<=64 with TPB=512 (proven R4).
//  * R15 FAILED: TPB=768 -> 1 block/CU (occupancy 33% < 37.5% single-block
//    ceiling) despite LDS 151KB and VGPR 56 fitting. Residency is NOT
//    predictable from LDS+VGPR at TPB>512; must be probed per size.
//  * R16: probe TPB=640 (10 waves, 1280 thr/CU for 2 blocks). Same LDS as R4.
//    640 divides 200 exactly in both GEMM tilings -> tail branches gone.
//  * R11: W1^T staged (stride 132) -> k-quad = one ds_read_b128; mid GEMMs
//    col-pair with paired W (stride 68). Bit-identical sums.
//  * R12/R14: degree-sorted row->group assignment; csr pre-memset to QPAD;
//    dinv-scale merged into CSR phase; conv weights staged by idle threads;
//    cW2 stride 81; fused rank+ord.
//  * R13 FAILED: global-mirror dual-path agg -> VGPR 68, occupancy halved.

#define TPB   640
#define GRID  512
#define MG    200
#define EPG   6400
#define EE    (512 * EPG)

// ---- LDS layout (byte offsets). Total 75,488 B -> 2 blocks/CU (151/160 KiB) ----
#define OFF_BUFX 0        // f32[201*36] rows 0..200 (row 200 = zeros); later topv[30][100] + conv W
#define OFF_HCUR 28944    // f32[200*36] h of current layer; Phase A/B: staged W1^T [32][132]
#define OFF_CSR  57744    // u8[7200]    CSR (rows padded to x4 entries, pad -> 200)
#define OFF_ROFF 64944    // i32[201] row offsets (padded units)
#define OFF_CNT  65760    // i32[200] degree counts   \ scl f32[201] aliases CNT..CUR
#define OFF_CUR  66560    // i32[200] cursors         /
#define OFF_DINV 67360    // f32[200]
#define OFF_H4   68160    // f32[200] sort key
#define OFF_ORD  69760    // i32[30]
#define OFF_BIAS 69880    // f32[64]  double-buffered layer bias
#define OFF_RED  70136    // f32[16] (+8 pad)
#define OFF_WREG 70208    // f32[1088] W2/W3 paired stage [16][8][2][4] stride 68
#define OFF_HIST 74560    // i32[32]  quad-count histogram -> offsets
#define OFF_PERM 74688    // i32[200] degree-sorted row permutation (desc)
#define SMEM_BYTES 75488

#define QPAD 0xC8C8C8C8u   // 4x index 200 (zero row) - exact no-op quad

__device__ __forceinline__ float fast_tanh(float x) {
    const float e = __expf(2.0f * x);
    return 1.0f - 2.0f / (e + 1.0f);
}

__global__ __launch_bounds__(TPB)
void dgcnn_kernel(
    const float* __restrict__ x,
    const int*   __restrict__ ei,
    const float* __restrict__ W1, const float* __restrict__ b1,
    const float* __restrict__ W2, const float* __restrict__ b2,
    const float* __restrict__ W3, const float* __restrict__ b3,
    const float* __restrict__ W4, const float* __restrict__ b4,
    const float* __restrict__ cW1, const float* __restrict__ cb1,
    const float* __restrict__ cW2, const float* __restrict__ cb2,
    const float* __restrict__ lW1, const float* __restrict__ lb1,
    const float* __restrict__ lW2, const float* __restrict__ lb2,
    __half* __restrict__ arch,     // [512][200][64] f16 archive of h1|h2
    float* __restrict__ out)
{
    extern __shared__ unsigned char smem[];
    float* bufX = (float*)(smem + OFF_BUFX);
    float* hcur = (float*)(smem + OFF_HCUR);
    unsigned char* csr = (unsigned char*)(smem + OFF_CSR);
    int*   roff = (int*)(smem + OFF_ROFF);
    int*   cnt  = (int*)(smem + OFF_CNT);
    int*   cur  = (int*)(smem + OFF_CUR);
    float* dinv = (float*)(smem + OFF_DINV);
    float* h4k  = (float*)(smem + OFF_H4);
    int*   ord  = (int*)(smem + OFF_ORD);
    float* bias = (float*)(smem + OFF_BIAS);
    float* red  = (float*)(smem + OFF_RED);
    float* wreg = (float*)(smem + OFF_WREG);
    int*   hist = (int*)(smem + OFF_HIST);
    int*   perm = (int*)(smem + OFF_PERM);

    const int g = blockIdx.x;
    const int t = threadIdx.x;
    const int gbase = g * MG;
    const float* xg   = x + (size_t)gbase * 128;
    const int*   srcp = ei + (size_t)g * EPG;
    const int*   dstp = ei + (size_t)EE + (size_t)g * EPG;

    // ---------------- Phase A: stage W1^T -> hcur [32][132] (stride 132 == 4 mod 32),
    // csr memset to QPAD (kills pad-fill phase), bias, zeros, hist=0. ----
    for (int idx = t; idx < 4096; idx += TPB)
        hcur[(idx & 31) * 132 + (idx >> 5)] = W1[idx];
    for (int idx = t; idx < 1800; idx += TPB)
        ((unsigned*)csr)[idx] = QPAD;
    if (t < 32) bias[t] = b1[t];
    if (t < MG) cnt[t] = 0;
    if (t >= 480 && t < 512) hist[t - 480] = 0;
    if (t >= 256 && t < 292) bufX[200 * 36 + (t - 256)] = 0.f;   // zero row 200
    __syncthreads();

    const int f32lane = t & 31;   // feature (output col) 0..31
    const int islot   = t >> 5;   // row slot 0..19

    // ---------------- Phase B: edge in-degree count (int4) + L1 GEMM, one phase ----------
    {
        const int4* d4p = (const int4*)dstp;
        for (int e4 = t; e4 < EPG / 4; e4 += TPB) {
            const int4 d4 = d4p[e4];
            atomicAdd(&cnt[d4.x - gbase], 1);
            atomicAdd(&cnt[d4.y - gbase], 1);
            atomicAdd(&cnt[d4.z - gbase], 1);
            atomicAdd(&cnt[d4.w - gbase], 1);
        }
    }
    {
        const int f = f32lane;
        const float* wt = hcur + f * 132;      // column f of W1, k-major
        const float4* xv = (const float4*)xg;
        #pragma unroll
        for (int p = 0; p < 2; ++p) {
            const int r0 = islot + 100 * p;    // rows r0, r0+20, r0+40, r0+60, r0+80
            float a0 = 0.f, a1 = 0.f, a2 = 0.f, a3 = 0.f, a4 = 0.f;
            #pragma unroll 2
            for (int k4 = 0; k4 < 32; ++k4) {
                const float4 w = *(const float4*)(wt + 4 * k4);
                float4 v;
                v = xv[(r0      ) * 32 + k4]; a0 += v.x*w.x + v.y*w.y + v.z*w.z + v.w*w.w;
                v = xv[(r0 + 20 ) * 32 + k4]; a1 += v.x*w.x + v.y*w.y + v.z*w.z + v.w*w.w;
                v = xv[(r0 + 40 ) * 32 + k4]; a2 += v.x*w.x + v.y*w.y + v.z*w.z + v.w*w.w;
                v = xv[(r0 + 60 ) * 32 + k4]; a3 += v.x*w.x + v.y*w.y + v.z*w.z + v.w*w.w;
                v = xv[(r0 + 80 ) * 32 + k4]; a4 += v.x*w.x + v.y*w.y + v.z*w.z + v.w*w.w;
            }
            bufX[(r0      ) * 36 + f] = a0;
            bufX[(r0 + 20 ) * 36 + f] = a1;
            bufX[(r0 + 40 ) * 36 + f] = a2;
            bufX[(r0 + 60 ) * 36 + f] = a3;
            bufX[(r0 + 80 ) * 36 + f] = a4;
        }
    }
    __syncthreads();

    // ---------------- Phase C: dinv + hist build + prefix scan over PADDED row lengths ----
    if (t >= 256 && t < 256 + MG) {
        const int i = t - 256;
        const int c = cnt[i];
        dinv[i] = 1.0f / sqrtf((float)(c + 1));
        int qc = (c + 4) >> 2;                 // padded quad count
        if (qc > 31) qc = 31;
        atomicAdd(&hist[31 - qc], 1);          // descending order
    }
    if (t < 64) {
        if (t == 0) roff[0] = 0;
        int carry = 0;
        #pragma unroll
        for (int c = 0; c < 4; ++c) {
            const int i = c * 64 + t;
            int v = (i < MG) ? ((cnt[i] + 4) & ~3) : 0;   // self-loop +1, pad to x4
            #pragma unroll
            for (int off = 1; off < 64; off <<= 1) {
                int u = __shfl_up(v, off);
                if (t >= (int)off) v += u;
            }
            if (i < MG) roff[i + 1] = carry + v;
            carry += __shfl(v, 63);
        }
    }
    __syncthreads();

    // ---------------- Phase D: self-loop entry + cursors + hist exclusive prefix ----------
    if (t < MG) {
        int p = roff[t];
        csr[p] = (unsigned char)t;
        cur[t] = p + 1;
    }
    if (t < 32) {
        const int own = hist[t];
        int v = own;
        #pragma unroll
        for (int off = 1; off < 32; off <<= 1) {
            int u = __shfl_up(v, off);
            if (t >= off) v += u;
        }
        hist[t] = v - own;   // exclusive offsets
    }
    __syncthreads();

    // ---------------- Phase E: CSR placement + dinv-scale bufX + perm scatter ------------
    {
        const int4* s4p = (const int4*)srcp;
        const int4* d4p = (const int4*)dstp;
        for (int e4 = t; e4 < EPG / 4; e4 += TPB) {
            const int4 s4 = s4p[e4];
            const int4 d4 = d4p[e4];
            int p;
            p = atomicAdd(&cur[d4.x - gbase], 1); csr[p] = (unsigned char)(s4.x - gbase);
            p = atomicAdd(&cur[d4.y - gbase], 1); csr[p] = (unsigned char)(s4.y - gbase);
            p = atomicAdd(&cur[d4.z - gbase], 1); csr[p] = (unsigned char)(s4.z - gbase);
            p = atomicAdd(&cur[d4.w - gbase], 1); csr[p] = (unsigned char)(s4.w - gbase);
        }
    }
    for (int r = islot; r < MG; r += 20) {
        bufX[r * 36 + f32lane] *= dinv[r];
    }
    if (t < MG) {
        int qc = (cnt[t] + 4) >> 2;
        if (qc > 31) qc = 31;
        const int pos = atomicAdd(&hist[31 - qc], 1);
        perm[pos] = t;   // perm: rows sorted by quad count, descending
    }
    __syncthreads();

    // agg: hcur[d][f] = tanh(dinv[d]*sum_{p} bufX[csr[p]][f] + bias[bb+f]);
    // 80 groups of 8 lanes. Pass 1: sorted pairs (ranks 0..159). Pass 2:
    // groups 40..79 (waves 5..9, whole-wave uniform) take singles reverse-rank
    // perm[239-dsl] (ranks 160..199) -> flat group totals.
    auto agg_layer = [&](int archOff, int bb) {
        const int f4  = (t & 7) << 2;
        const int dsl = t >> 3;   // 0..79

        auto finish = [&](int d, float a0, float a1, float a2, float a3) {
            const float dv = dinv[d];
            const float o0 = fast_tanh(dv * a0 + bias[bb + f4 + 0]);
            const float o1 = fast_tanh(dv * a1 + bias[bb + f4 + 1]);
            const float o2 = fast_tanh(dv * a2 + bias[bb + f4 + 2]);
            const float o3 = fast_tanh(dv * a3 + bias[bb + f4 + 3]);
            *(float4*)(hcur + d * 36 + f4) = make_float4(o0, o1, o2, o3);
            if (archOff >= 0) {
                const __half2 p01 = __floats2half2_rn(o0, o1);
                const __half2 p23 = __floats2half2_rn(o2, o3);
                __half2* dst = (__half2*)(arch + (size_t)(gbase + d) * 64 + archOff + f4);
                dst[0] = p01;
                dst[1] = p23;
            }
        };

        auto pair_rows = [&](int da, int db) {
            const int p1a = roff[da + 1], p1b = roff[db + 1];
            int pa = roff[da], pb = roff[db];
            const int na = (p1a - pa) >> 2, nb = (p1b - pb) >> 2;
            const int iters = na > nb ? na : nb;
            unsigned qa = *(const unsigned*)(csr + pa);
            unsigned qb = *(const unsigned*)(csr + pb);
            float a0=0.f,a1=0.f,a2=0.f,a3=0.f, c0=0.f,c1=0.f,c2=0.f,c3=0.f;
            for (int i = 0; i < iters; ++i) {
                pa += 4; pb += 4;
                const unsigned qa_n = (pa < p1a) ? *(const unsigned*)(csr + pa) : QPAD;
                const unsigned qb_n = (pb < p1b) ? *(const unsigned*)(csr + pb) : QPAD;
                float4 v;
                v = *(const float4*)(bufX + (qa & 255u) * 36 + f4);         a0+=v.x; a1+=v.y; a2+=v.z; a3+=v.w;
                v = *(const float4*)(bufX + ((qa >> 8) & 255u) * 36 + f4);  a0+=v.x; a1+=v.y; a2+=v.z; a3+=v.w;
                v = *(const float4*)(bufX + ((qa >> 16) & 255u) * 36 + f4); a0+=v.x; a1+=v.y; a2+=v.z; a3+=v.w;
                v = *(const float4*)(bufX + (qa >> 24) * 36 + f4);          a0+=v.x; a1+=v.y; a2+=v.z; a3+=v.w;
                v = *(const float4*)(bufX + (qb & 255u) * 36 + f4);         c0+=v.x; c1+=v.y; c2+=v.z; c3+=v.w;
                v = *(const float4*)(bufX + ((qb >> 8) & 255u) * 36 + f4);  c0+=v.x; c1+=v.y; c2+=v.z; c3+=v.w;
                v = *(const float4*)(bufX + ((qb >> 16) & 255u) * 36 + f4); c0+=v.x; c1+=v.y; c2+=v.z; c3+=v.w;
                v = *(const float4*)(bufX + (qb >> 24) * 36 + f4);          c0+=v.x; c1+=v.y; c2+=v.z; c3+=v.w;
                qa = qa_n; qb = qb_n;
            }
            finish(da, a0, a1, a2, a3);
            finish(db, c0, c1, c2, c3);
        };

        auto one_row = [&](int d) {
            const int p1 = roff[d + 1];
            int p = roff[d];
            const int iters = (p1 - p) >> 2;
            unsigned q = *(const unsigned*)(csr + p);
            float a0=0.f,a1=0.f,a2=0.f,a3=0.f;
            for (int i = 0; i < iters; ++i) {
                p += 4;
                const unsigned q_n = (p < p1) ? *(const unsigned*)(csr + p) : QPAD;
                float4 v;
                v = *(const float4*)(bufX + (q & 255u) * 36 + f4);         a0+=v.x; a1+=v.y; a2+=v.z; a3+=v.w;
                v = *(const float4*)(bufX + ((q >> 8) & 255u) * 36 + f4);  a0+=v.x; a1+=v.y; a2+=v.z; a3+=v.w;
                v = *(const float4*)(bufX + ((q >> 16) & 255u) * 36 + f4); a0+=v.x; a1+=v.y; a2+=v.z; a3+=v.w;
                v = *(const float4*)(bufX + (q >> 24) * 36 + f4);          a0+=v.x; a1+=v.y; a2+=v.z; a3+=v.w;
                q = q_n;
            }
            finish(d, a0, a1, a2, a3);
        };

        // Pass 1: group g takes sorted pair (perm[2g], perm[2g+1]), g = 0..79.
        // Pass 2: groups 40..79 take singles perm[239-dsl] (ranks 160..199,
        // reverse-rank -> heaviest of these groups gets lightest single).
        pair_rows(perm[2 * dsl], perm[2 * dsl + 1]);
        if (dsl >= 40) one_row(perm[239 - dsl]);
    };

    auto gemm_mid = [&](const float* __restrict__ src) {
        // bufX = (src[200x32] @ W[32x32]) scaled by dinv[row]; W staged paired in
        // wreg: [f2][k4][c][4] stride 68 (== 4 mod 32, 2-way banks). Col-pair x
        // 5-row mapping (40 slots, exact): each src b128 feeds 8 FMAs.
        const int f2 = t & 15;    // column pair: cols 2*f2, 2*f2+1
        const int sl = t >> 4;    // row slot 0..39
        const float* wp = wreg + f2 * 68;
        float a0A=0.f,a1A=0.f,a2A=0.f,a3A=0.f,a4A=0.f;
        float a0B=0.f,a1B=0.f,a2B=0.f,a3B=0.f,a4B=0.f;
        #pragma unroll 2
        for (int k4 = 0; k4 < 8; ++k4) {
            const float4 wA = *(const float4*)(wp + k4 * 8);
            const float4 wB = *(const float4*)(wp + k4 * 8 + 4);
            float4 v;
            v = *(const float4*)(src + (sl       ) * 36 + 4 * k4);
            a0A += v.x*wA.x + v.y*wA.y + v.z*wA.z + v.w*wA.w;
            a0B += v.x*wB.x + v.y*wB.y + v.z*wB.z + v.w*wB.w;
            v = *(const float4*)(src + (sl + 40  ) * 36 + 4 * k4);
            a1A += v.x*wA.x + v.y*wA.y + v.z*wA.z + v.w*wA.w;
            a1B += v.x*wB.x + v.y*wB.y + v.z*wB.z + v.w*wB.w;
            v = *(const float4*)(src + (sl + 80  ) * 36 + 4 * k4);
            a2A += v.x*wA.x + v.y*wA.y + v.z*wA.z + v.w*wA.w;
            a2B += v.x*wB.x + v.y*wB.y + v.z*wB.z + v.w*wB.w;
            v = *(const float4*)(src + (sl + 120 ) * 36 + 4 * k4);
            a3A += v.x*wA.x + v.y*wA.y + v.z*wA.z + v.w*wA.w;
            a3B += v.x*wB.x + v.y*wB.y + v.z*wB.z + v.w*wB.w;
            v = *(const float4*)(src + (sl + 160 ) * 36 + 4 * k4);
            a4A += v.x*wA.x + v.y*wA.y + v.z*wA.z + v.w*wA.w;
            a4B += v.x*wB.x + v.y*wB.y + v.z*wB.z + v.w*wB.w;
        }
        const int c0 = 2 * f2;
        *(float2*)(bufX + (sl       ) * 36 + c0) = make_float2(dinv[sl      ] * a0A, dinv[sl      ] * a0B);
        *(float2*)(bufX + (sl + 40  ) * 36 + c0) = make_float2(dinv[sl + 40 ] * a1A, dinv[sl + 40 ] * a1B);
        *(float2*)(bufX + (sl + 80  ) * 36 + c0) = make_float2(dinv[sl + 80 ] * a2A, dinv[sl + 80 ] * a2B);
        *(float2*)(bufX + (sl + 120 ) * 36 + c0) = make_float2(dinv[sl + 120] * a3A, dinv[sl + 120] * a3B);
        *(float2*)(bufX + (sl + 160 ) * 36 + c0) = make_float2(dinv[sl + 160] * a4A, dinv[sl + 160] * a4B);
    };

    // paired-W staging: wreg[f2*68 + k4*8 + c*4 + j] = W[(4k4+j)*32 + 2f2+c]
    auto stage_w_paired = [&](const float* __restrict__ W) {
        for (int idx = t; idx < 1024; idx += TPB) {
            const int k = idx >> 5, f = idx & 31;
            wreg[(f >> 1) * 68 + (k >> 2) * 8 + ((f & 1) << 2) + (k & 3)] = W[idx];
        }
    };

    // ---------------- Layer 1 agg (+ stage W2/b2 in-phase, bias double-buffer) --------
    agg_layer(0, 0);    // h1 -> arch[:,0:32)
    stage_w_paired(W2);
    if (t < 32) bias[32 + t] = b2[t];
    __syncthreads();

    // ---------------- Layer 2 ----------------
    gemm_mid(hcur);
    __syncthreads();
    agg_layer(32, 32);  // h2 -> arch[:,32:64)
    stage_w_paired(W3);
    if (t < 32) bias[t] = b3[t];
    __syncthreads();

    // ---------------- Layer 3 ----------------
    gemm_mid(hcur);
    __syncthreads();
    agg_layer(-1, 0);   // h3 stays in hcur (f32), not archived
    __syncthreads();

    // conv weight staging targets (bufX dead after agg3 barrier)
    float* topv = bufX;           // [30][100] = 3000 floats
    float* cw   = bufX + 3008;    // cW1: [0,1552)  cW2 stride-81: [1552,5695); ends 7151 <= 7236

    // ---------------- Layer 4 (Fout=1): scl = dinv * (h3 @ W4); scl[200]=0 ----------------
    // Idle threads 256..639 stage cW1; threads 208..255 stage conv biases.
    float* scl = (float*)(smem + OFF_CNT);   // 400 floats available (cnt+cur dead)
    if (t < MG) {
        float a = 0.f;
        #pragma unroll 8
        for (int k = 0; k < 32; ++k) a += hcur[t * 36 + k] * W4[k];
        scl[t] = dinv[t] * a;
    }
    if (t == 200) scl[200] = 0.f;
    if (t >= 256) {
        for (int idx = t - 256; idx < 1552; idx += TPB - 256) cw[idx] = cW1[idx];
    } else if (t >= 208 && t < 224) {
        bias[t - 208] = cb1[t - 208];
    } else if (t >= 224 && t < 256) {
        bias[16 + (t - 224)] = cb2[t - 224];
    }
    __syncthreads();
    // h4k gather; idle threads stage cW2 at stride 81 (odd -> no bank aliasing in conv2)
    if (t < MG) {
        const int p0 = roff[t], p1 = roff[t + 1];
        float s = 0.f;
        for (int p = p0; p < p1; p += 4) {
            const unsigned q = *(const unsigned*)(csr + p);
            s += scl[q & 255u] + scl[(q >> 8) & 255u]
               + scl[(q >> 16) & 255u] + scl[q >> 24];
        }
        h4k[t] = fast_tanh(dinv[t] * s + b4[0]);
    }
    if (t >= 256) {
        for (int idx = t - 256; idx < 2560; idx += TPB - 256) {
            const int o = idx / 80, r = idx - o * 80;
            cw[1552 + o * 81 + r] = cW2[idx];
        }
    }
    __syncthreads();

    // ---------------- SortPool: fused exact stable rank + ord scatter ----------------
    // (desc value, asc index). Each of 200 threads ranks itself over all 200
    // (same-address LDS reads broadcast -> free); scatter ord directly.
    if (t < MG) {
        const float vi = h4k[t];
        int r = 0;
        for (int j = 0; j < MG; ++j) {
            const float vj = h4k[j];
            r += (vj > vi || (vj == vi && j < t)) ? 1 : 0;
        }
        if (r < 30) ord[r] = t;
    }
    __syncthreads();

    // ---------------- Gather top-30 features ----------
    for (int idx = t; idx < 2910; idx += TPB) {   // 30*97 grid-stride
        const int kk = idx / 97;
        const int ff = idx - kk * 97;
        const int nd = ord[kk];
        float v;
        if      (ff < 64) v = __half2float(arch[(size_t)(gbase + nd) * 64 + ff]);
        else if (ff < 96) v = hcur[nd * 36 + (ff - 64)];   // h3, f32
        else              v = h4k[nd];
        topv[kk * 100 + ff] = v;
    }
    __syncthreads();

    // conv scratch in hcur (dead after gather barrier)
    float* c1p2 = hcur;           // [16][30]
    float* c1pl = hcur + 480;     // [16][16]
    float* flat = hcur + 736;     // [352]
    float* hlin = hcur + 1088;    // [128]

    // ---------------- Conv1 (97->16 per slot) + ReLU ----------------
    if (t < 480) {
        const int o  = t & 15;
        const int tt = t >> 4;
        float a = bias[o];
        const float* wrow = cw + o * 97;
        const float* trow = topv + tt * 100;
        #pragma unroll 4
        for (int f = 0; f < 97; ++f) a += wrow[f] * trow[f];
        c1p2[o * 30 + tt] = fmaxf(a, 0.f);
    }
    __syncthreads();

    // ---------------- MaxPool1d(2,2): 30 -> 15 ----------------
    if (t < 240) {
        const int o  = t & 15;
        const int tp = t >> 4;
        c1pl[o * 16 + tp] = fmaxf(c1p2[o * 30 + 2 * tp], c1p2[o * 30 + 2 * tp + 1]);
    }
    __syncthreads();

    // ---------------- Conv2 (16->32, k=5) + ReLU -> flat; init hlin ----------------
    if (t < 352) {
        const int o  = t & 31;
        const int tt = t >> 5;
        float a = bias[16 + o];
        const float* w2r = cw + 1552 + o * 81;
        #pragma unroll
        for (int i2 = 0; i2 < 16; ++i2) {
            #pragma unroll
            for (int kk = 0; kk < 5; ++kk)
                a += w2r[i2 * 5 + kk] * c1pl[i2 * 16 + tt + kk];
        }
        flat[o * 11 + tt] = fmaxf(a, 0.f);
    } else if (t >= 352 && t < 480) {
        hlin[t - 352] = lb1[t - 352];
    }
    __syncthreads();

    // ---------------- Linear 352->128 (split-K over 4 groups of 88) ----------------
    if (t < 512) {
        const int f  = t & 127;
        const int kc = t >> 7;   // 0..3
        float a = 0.f;
        const int k0 = kc * 88;
        #pragma unroll 4
        for (int kk = k0; kk < k0 + 88; ++kk) a += flat[kk] * lW1[kk * 128 + f];
        atomicAdd(&hlin[f], a);
    }
    __syncthreads();

    // ---------------- ReLU -> Linear 128->1 -> sigmoid ----------------
    if (t < 128) {
        float p = fmaxf(hlin[t], 0.f) * lW2[t];
        #pragma unroll
        for (int off = 32; off > 0; off >>= 1) p += __shfl_down(p, off);
        if ((t & 63) == 0) red[t >> 6] = p;
    }
    __syncthreads();
    if (t == 0) {
        const float z = red[0] + red[1] + lb2[0];
        out[g] = 1.f / (1.f + expf(-z));
    }
}

extern "C" void kernel_launch(void* const* d_in, const int* in_sizes, int n_in,
                              void* d_out, int out_size, void* d_ws, size_t ws_size,
                              hipStream_t stream) {
    (void)in_sizes; (void)n_in; (void)out_size; (void)ws_size;
    const float* x   = (const float*)d_in[0];
    const int*   ei  = (const int*)d_in[1];
    const float* W1  = (const float*)d_in[3];  const float* b1  = (const float*)d_in[4];
    const float* W2  = (const float*)d_in[5];  const float* b2  = (const float*)d_in[6];
    const float* W3  = (const float*)d_in[7];  const float* b3  = (const float*)d_in[8];
    const float* W4  = (const float*)d_in[9];  const float* b4  = (const float*)d_in[10];
    const float* cW1 = (const float*)d_in[11]; const float* cb1 = (const float*)d_in[12];
    const float* cW2 = (const float*)d_in[13]; const float* cb2 = (const float*)d_in[14];
    const float* lW1 = (const float*)d_in[15]; const float* lb1 = (const float*)d_in[16];
    const float* lW2 = (const float*)d_in[17]; const float* lb2 = (const float*)d_in[18];
    float* out = (float*)d_out;
    __half* arch = (__half*)d_ws;   // needs 512*200*64*2 = 13.1 MB

    hipFuncSetAttribute((const void*)dgcnn_kernel,
                        hipFuncAttributeMaxDynamicSharedMemorySize, SMEM_BYTES);

    dgcnn_kernel<<<GRID, TPB, SMEM_BYTES, stream>>>(
        x, ei, W1, b1, W2, b2, W3, b3, W4, b4,
        cW1, cb1, cW2, cb2, lW1, lb1, lW2, lb2, arch, out);
}

// Round 7
// 242.069 us; speedup vs baseline: 1.1104x; 1.1059x over previous
//
#include <hip/hip_runtime.h>
#include <hip/hip_fp16.h>

// DGCNN forward, fully fused: one workgroup per graph, TPB=512 (8 waves),
// 2 blocks/CU co-resident. f32 on the entire sort-key chain; h1/h2 archived
// to global f16 (conv features only); h3 read back from LDS f32.
//
// Occupancy rules learned R3-R16 (MI355X):
//  * NO launch_bounds min-waves / waves_per_eu hints -> allocator over-shrinks.
//  * 2 blocks co-schedule ONLY at TPB=512 with VGPR<=64 (R4 proven at 60).
//    R15 (TPB=768, VGPR 56) and R16 (TPB=640, VGPR 68) both fell to 1
//    block/CU. TPB=512 is the operating point; 3 blocks/CU is impossible
//    (bufX+hcur = 57.7KB > 53.3KB 3-block LDS budget). 16 waves/CU is a cap.
//  * R11: mid GEMMs col-pair x 6-row with paired W (stride 68).
//  * R12/R14: degree-sorted row->group agg assignment; csr pre-memset QPAD;
//    dinv-scale merged into CSR phase; conv weights staged by idle threads;
//    cW2 stride 81; fused rank+ord.
//  * R13 FAILED: global-mirror dual-path agg -> VGPR 68. No per-entry 64-bit
//    address streams in the agg loop.
//  * R17: Phase B was latency-stalled: x loads were 32-lane BROADCAST (32
//    distinct B per instr; ~6KB in flight/CU << 22KB latency-BW product).
//    New mapping: wave w owns output cols 4w..4w+3, lane owns a row -> every
//    x load is 64 distinct 16B lines/instr; W1 staged row-major [128][36] and
//    read as wave-uniform broadcast. L1 absorbs the 8x cross-wave x re-read.
//    FMA expression shape unchanged -> bit-identical.

#define TPB   512
#define GRID  512
#define MG    200
#define EPG   6400
#define EE    (512 * EPG)

// ---- LDS layout (byte offsets). Total 75,488 B -> 2 blocks/CU (151/160 KiB) ----
#define OFF_BUFX 0        // f32[201*36] rows 0..200 (row 200 = zeros); later topv[30][100] + conv W
#define OFF_HCUR 28944    // f32[200*36] h of current layer; Phase A/B: staged W1 row-major [128][36]
#define OFF_CSR  57744    // u8[7200]    CSR (rows padded to x4 entries, pad -> 200)
#define OFF_ROFF 64944    // i32[201] row offsets (padded units)
#define OFF_CNT  65760    // i32[200] degree counts   \ scl f32[201] aliases CNT..CUR
#define OFF_CUR  66560    // i32[200] cursors         /
#define OFF_DINV 67360    // f32[200]
#define OFF_H4   68160    // f32[200] sort key
#define OFF_ORD  69760    // i32[30]
#define OFF_BIAS 69880    // f32[64]  double-buffered layer bias
#define OFF_RED  70136    // f32[16] (+8 pad)
#define OFF_WREG 70208    // f32[1088] W2/W3 paired stage [16][8][2][4] stride 68
#define OFF_HIST 74560    // i32[32]  quad-count histogram -> offsets
#define OFF_PERM 74688    // i32[200] degree-sorted row permutation (desc)
#define SMEM_BYTES 75488

#define QPAD 0xC8C8C8C8u   // 4x index 200 (zero row) - exact no-op quad

__device__ __forceinline__ float fast_tanh(float x) {
    const float e = __expf(2.0f * x);
    return 1.0f - 2.0f / (e + 1.0f);
}

__global__ __launch_bounds__(TPB)
void dgcnn_kernel(
    const float* __restrict__ x,
    const int*   __restrict__ ei,
    const float* __restrict__ W1, const float* __restrict__ b1,
    const float* __restrict__ W2, const float* __restrict__ b2,
    const float* __restrict__ W3, const float* __restrict__ b3,
    const float* __restrict__ W4, const float* __restrict__ b4,
    const float* __restrict__ cW1, const float* __restrict__ cb1,
    const float* __restrict__ cW2, const float* __restrict__ cb2,
    const float* __restrict__ lW1, const float* __restrict__ lb1,
    const float* __restrict__ lW2, const float* __restrict__ lb2,
    __half* __restrict__ arch,     // [512][200][64] f16 archive of h1|h2
    float* __restrict__ out)
{
    extern __shared__ unsigned char smem[];
    float* bufX = (float*)(smem + OFF_BUFX);
    float* hcur = (float*)(smem + OFF_HCUR);
    unsigned char* csr = (unsigned char*)(smem + OFF_CSR);
    int*   roff = (int*)(smem + OFF_ROFF);
    int*   cnt  = (int*)(smem + OFF_CNT);
    int*   cur  = (int*)(smem + OFF_CUR);
    float* dinv = (float*)(smem + OFF_DINV);
    float* h4k  = (float*)(smem + OFF_H4);
    int*   ord  = (int*)(smem + OFF_ORD);
    float* bias = (float*)(smem + OFF_BIAS);
    float* red  = (float*)(smem + OFF_RED);
    float* wreg = (float*)(smem + OFF_WREG);
    int*   hist = (int*)(smem + OFF_HIST);
    int*   perm = (int*)(smem + OFF_PERM);

    const int g = blockIdx.x;
    const int t = threadIdx.x;
    const int gbase = g * MG;
    const float* xg   = x + (size_t)gbase * 128;
    const int*   srcp = ei + (size_t)g * EPG;
    const int*   dstp = ei + (size_t)EE + (size_t)g * EPG;

    // ---------------- Phase A: stage W1 row-major -> hcur [128][36] (16B-aligned rows),
    // csr memset to QPAD (kills pad-fill phase), bias, zeros, hist=0. ----
    for (int idx = t; idx < 4096; idx += TPB)
        hcur[(idx >> 5) * 36 + (idx & 31)] = W1[idx];
    for (int idx = t; idx < 1800; idx += TPB)
        ((unsigned*)csr)[idx] = QPAD;
    if (t < 32) bias[t] = b1[t];
    if (t < MG) cnt[t] = 0;
    if (t >= 480) hist[t - 480] = 0;
    if (t >= 256 && t < 292) bufX[200 * 36 + (t - 256)] = 0.f;   // zero row 200
    __syncthreads();

    const int f32lane = t & 31;   // feature lane 0..31
    const int islot   = t >> 5;   // slot 0..15

    // ---------------- Phase B: edge in-degree count (int4) + L1 GEMM, one phase ----------
    // GEMM mapping (R17): wave w8 owns output cols 4*w8..4*w8+3; lane owns a
    // row -> x loads are 64 DISTINCT 16B lines per instruction (full BW);
    // W1 read as wave-uniform float4 broadcast. Writes UNSCALED xw (dinv
    // applied in Phase E - identical arithmetic).
    {
        const int4* d4p = (const int4*)dstp;
        for (int e4 = t; e4 < EPG / 4; e4 += TPB) {
            const int4 d4 = d4p[e4];
            atomicAdd(&cnt[d4.x - gbase], 1);
            atomicAdd(&cnt[d4.y - gbase], 1);
            atomicAdd(&cnt[d4.z - gbase], 1);
            atomicAdd(&cnt[d4.w - gbase], 1);
        }
    }
    {
        const int l63 = t & 63;        // row lane within wave
        const int w8  = t >> 6;        // wave id 0..7
        const int c4  = w8 * 4;        // this wave's column quad
        const float4* xv = (const float4*)xg;
        const float* Wm = hcur;        // W1 row-major [128][36]

        // Pass A: rows l63 and 64+l63, 2-row interleave (unroll 1: VGPR cap)
        {
            const int ra = l63, rb = 64 + l63;
            float4 accA = make_float4(0.f, 0.f, 0.f, 0.f);
            float4 accB = make_float4(0.f, 0.f, 0.f, 0.f);
            #pragma unroll 1
            for (int k4 = 0; k4 < 32; ++k4) {
                const float4 xa = xv[ra * 32 + k4];
                const float4 xb = xv[rb * 32 + k4];
                const float4 w0 = *(const float4*)(Wm + (4 * k4 + 0) * 36 + c4);
                const float4 w1 = *(const float4*)(Wm + (4 * k4 + 1) * 36 + c4);
                const float4 w2 = *(const float4*)(Wm + (4 * k4 + 2) * 36 + c4);
                const float4 w3 = *(const float4*)(Wm + (4 * k4 + 3) * 36 + c4);
                accA.x += xa.x*w0.x + xa.y*w1.x + xa.z*w2.x + xa.w*w3.x;
                accA.y += xa.x*w0.y + xa.y*w1.y + xa.z*w2.y + xa.w*w3.y;
                accA.z += xa.x*w0.z + xa.y*w1.z + xa.z*w2.z + xa.w*w3.z;
                accA.w += xa.x*w0.w + xa.y*w1.w + xa.z*w2.w + xa.w*w3.w;
                accB.x += xb.x*w0.x + xb.y*w1.x + xb.z*w2.x + xb.w*w3.x;
                accB.y += xb.x*w0.y + xb.y*w1.y + xb.z*w2.y + xb.w*w3.y;
                accB.z += xb.x*w0.z + xb.y*w1.z + xb.z*w2.z + xb.w*w3.z;
                accB.w += xb.x*w0.w + xb.y*w1.w + xb.z*w2.w + xb.w*w3.w;
            }
            *(float4*)(bufX + ra * 36 + c4) = accA;
            *(float4*)(bufX + rb * 36 + c4) = accB;
        }
        // Pass B: row 128+l63
        {
            const int rc = 128 + l63;
            float4 acc = make_float4(0.f, 0.f, 0.f, 0.f);
            #pragma unroll 2
            for (int k4 = 0; k4 < 32; ++k4) {
                const float4 xc = xv[rc * 32 + k4];
                const float4 w0 = *(const float4*)(Wm + (4 * k4 + 0) * 36 + c4);
                const float4 w1 = *(const float4*)(Wm + (4 * k4 + 1) * 36 + c4);
                const float4 w2 = *(const float4*)(Wm + (4 * k4 + 2) * 36 + c4);
                const float4 w3 = *(const float4*)(Wm + (4 * k4 + 3) * 36 + c4);
                acc.x += xc.x*w0.x + xc.y*w1.x + xc.z*w2.x + xc.w*w3.x;
                acc.y += xc.x*w0.y + xc.y*w1.y + xc.z*w2.y + xc.w*w3.y;
                acc.z += xc.x*w0.z + xc.y*w1.z + xc.z*w2.z + xc.w*w3.z;
                acc.w += xc.x*w0.w + xc.y*w1.w + xc.z*w2.w + xc.w*w3.w;
            }
            *(float4*)(bufX + rc * 36 + c4) = acc;
        }
        // Tail rows 192..199: wave w8 -> row 192+w8; lanes 0..31 per-column.
        if (l63 < 32) {
            const int row = 192 + w8;
            const int f = l63;
            float a = 0.f;
            #pragma unroll 2
            for (int k4 = 0; k4 < 32; ++k4) {
                const float4 xq = xv[row * 32 + k4];
                a += xq.x * Wm[(4 * k4 + 0) * 36 + f]
                   + xq.y * Wm[(4 * k4 + 1) * 36 + f]
                   + xq.z * Wm[(4 * k4 + 2) * 36 + f]
                   + xq.w * Wm[(4 * k4 + 3) * 36 + f];
            }
            bufX[row * 36 + f] = a;
        }
    }
    __syncthreads();

    // ---------------- Phase C: dinv + hist build + prefix scan over PADDED row lengths ----
    if (t >= 256 && t < 256 + MG) {
        const int i = t - 256;
        const int c = cnt[i];
        dinv[i] = 1.0f / sqrtf((float)(c + 1));
        int qc = (c + 4) >> 2;                 // padded quad count
        if (qc > 31) qc = 31;
        atomicAdd(&hist[31 - qc], 1);          // descending order
    }
    if (t < 64) {
        if (t == 0) roff[0] = 0;
        int carry = 0;
        #pragma unroll
        for (int c = 0; c < 4; ++c) {
            const int i = c * 64 + t;
            int v = (i < MG) ? ((cnt[i] + 4) & ~3) : 0;   // self-loop +1, pad to x4
            #pragma unroll
            for (int off = 1; off < 64; off <<= 1) {
                int u = __shfl_up(v, off);
                if (t >= (int)off) v += u;
            }
            if (i < MG) roff[i + 1] = carry + v;
            carry += __shfl(v, 63);
        }
    }
    __syncthreads();

    // ---------------- Phase D: self-loop entry + cursors + hist exclusive prefix ----------
    if (t < MG) {
        int p = roff[t];
        csr[p] = (unsigned char)t;
        cur[t] = p + 1;
    }
    if (t < 32) {
        const int own = hist[t];
        int v = own;
        #pragma unroll
        for (int off = 1; off < 32; off <<= 1) {
            int u = __shfl_up(v, off);
            if (t >= off) v += u;
        }
        hist[t] = v - own;   // exclusive offsets
    }
    __syncthreads();

    // ---------------- Phase E: CSR placement + dinv-scale bufX + perm scatter ------------
    {
        const int4* s4p = (const int4*)srcp;
        const int4* d4p = (const int4*)dstp;
        for (int e4 = t; e4 < EPG / 4; e4 += TPB) {
            const int4 s4 = s4p[e4];
            const int4 d4 = d4p[e4];
            int p;
            p = atomicAdd(&cur[d4.x - gbase], 1); csr[p] = (unsigned char)(s4.x - gbase);
            p = atomicAdd(&cur[d4.y - gbase], 1); csr[p] = (unsigned char)(s4.y - gbase);
            p = atomicAdd(&cur[d4.z - gbase], 1); csr[p] = (unsigned char)(s4.z - gbase);
            p = atomicAdd(&cur[d4.w - gbase], 1); csr[p] = (unsigned char)(s4.w - gbase);
        }
    }
    for (int r = islot; r < MG; r += 16) {
        bufX[r * 36 + f32lane] *= dinv[r];
    }
    if (t < MG) {
        int qc = (cnt[t] + 4) >> 2;
        if (qc > 31) qc = 31;
        const int pos = atomicAdd(&hist[31 - qc], 1);
        perm[pos] = t;   // perm: rows sorted by quad count, descending
    }
    __syncthreads();

    // agg: hcur[d][f] = tanh(dinv[d]*sum_{p} bufX[csr[p]][f] + bias[bb+f]);
    // 2-row interleaved + csr-quad prefetch; degree-sorted perm assignment with
    // group-TOTAL balancing (pass1 desc + pass2 reverse-rank, no sync between).
    auto agg_layer = [&](int archOff, int bb) {
        const int f4  = (t & 7) << 2;
        const int dsl = t >> 3;   // 0..63

        auto finish = [&](int d, float a0, float a1, float a2, float a3) {
            const float dv = dinv[d];
            const float o0 = fast_tanh(dv * a0 + bias[bb + f4 + 0]);
            const float o1 = fast_tanh(dv * a1 + bias[bb + f4 + 1]);
            const float o2 = fast_tanh(dv * a2 + bias[bb + f4 + 2]);
            const float o3 = fast_tanh(dv * a3 + bias[bb + f4 + 3]);
            *(float4*)(hcur + d * 36 + f4) = make_float4(o0, o1, o2, o3);
            if (archOff >= 0) {
                const __half2 p01 = __floats2half2_rn(o0, o1);
                const __half2 p23 = __floats2half2_rn(o2, o3);
                __half2* dst = (__half2*)(arch + (size_t)(gbase + d) * 64 + archOff + f4);
                dst[0] = p01;
                dst[1] = p23;
            }
        };

        auto pair_rows = [&](int da, int db) {
            const int p1a = roff[da + 1], p1b = roff[db + 1];
            int pa = roff[da], pb = roff[db];
            const int na = (p1a - pa) >> 2, nb = (p1b - pb) >> 2;
            const int iters = na > nb ? na : nb;
            unsigned qa = *(const unsigned*)(csr + pa);
            unsigned qb = *(const unsigned*)(csr + pb);
            float a0=0.f,a1=0.f,a2=0.f,a3=0.f, c0=0.f,c1=0.f,c2=0.f,c3=0.f;
            for (int i = 0; i < iters; ++i) {
                pa += 4; pb += 4;
                const unsigned qa_n = (pa < p1a) ? *(const unsigned*)(csr + pa) : QPAD;
                const unsigned qb_n = (pb < p1b) ? *(const unsigned*)(csr + pb) : QPAD;
                float4 v;
                v = *(const float4*)(bufX + (qa & 255u) * 36 + f4);         a0+=v.x; a1+=v.y; a2+=v.z; a3+=v.w;
                v = *(const float4*)(bufX + ((qa >> 8) & 255u) * 36 + f4);  a0+=v.x; a1+=v.y; a2+=v.z; a3+=v.w;
                v = *(const float4*)(bufX + ((qa >> 16) & 255u) * 36 + f4); a0+=v.x; a1+=v.y; a2+=v.z; a3+=v.w;
                v = *(const float4*)(bufX + (qa >> 24) * 36 + f4);          a0+=v.x; a1+=v.y; a2+=v.z; a3+=v.w;
                v = *(const float4*)(bufX + (qb & 255u) * 36 + f4);         c0+=v.x; c1+=v.y; c2+=v.z; c3+=v.w;
                v = *(const float4*)(bufX + ((qb >> 8) & 255u) * 36 + f4);  c0+=v.x; c1+=v.y; c2+=v.z; c3+=v.w;
                v = *(const float4*)(bufX + ((qb >> 16) & 255u) * 36 + f4); c0+=v.x; c1+=v.y; c2+=v.z; c3+=v.w;
                v = *(const float4*)(bufX + (qb >> 24) * 36 + f4);          c0+=v.x; c1+=v.y; c2+=v.z; c3+=v.w;
                qa = qa_n; qb = qb_n;
            }
            finish(da, a0, a1, a2, a3);
            finish(db, c0, c1, c2, c3);
        };

        auto one_row = [&](int d) {
            const int p1 = roff[d + 1];
            int p = roff[d];
            const int iters = (p1 - p) >> 2;
            unsigned q = *(const unsigned*)(csr + p);
            float a0=0.f,a1=0.f,a2=0.f,a3=0.f;
            for (int i = 0; i < iters; ++i) {
                p += 4;
                const unsigned q_n = (p < p1) ? *(const unsigned*)(csr + p) : QPAD;
                float4 v;
                v = *(const float4*)(bufX + (q & 255u) * 36 + f4);         a0+=v.x; a1+=v.y; a2+=v.z; a3+=v.w;
                v = *(const float4*)(bufX + ((q >> 8) & 255u) * 36 + f4);  a0+=v.x; a1+=v.y; a2+=v.z; a3+=v.w;
                v = *(const float4*)(bufX + ((q >> 16) & 255u) * 36 + f4); a0+=v.x; a1+=v.y; a2+=v.z; a3+=v.w;
                v = *(const float4*)(bufX + (q >> 24) * 36 + f4);          a0+=v.x; a1+=v.y; a2+=v.z; a3+=v.w;
                q = q_n;
            }
            finish(d, a0, a1, a2, a3);
        };

        // Pass 1: group g takes sorted pair (perm[2g], perm[2g+1])  [ranks 0..127].
        // Pass 2 (reverse-rank): heaviest pass1 groups get lightest pass2 items.
        // Wave 0 (dsl<8) takes the 8 tiny pairs; groups 8..63 singles perm[191-dsl].
        pair_rows(perm[2 * dsl], perm[2 * dsl + 1]);
        if (dsl < 8) pair_rows(perm[184 + 7 - dsl], perm[192 + 7 - dsl]);
        else         one_row(perm[191 - dsl]);
    };

    auto gemm_mid = [&](const float* __restrict__ src) {
        // bufX = (src[200x32] @ W[32x32]) scaled by dinv[row]; W staged paired in
        // wreg: [f2][k4][c][4] stride 68 (== 4 mod 32, 2-way banks). Col-pair x
        // 6-row mapping: each src b128 feeds 8 FMAs (halves activation reads).
        const int f2 = t & 15;    // column pair: cols 2*f2, 2*f2+1
        const int sl = t >> 4;    // row slot 0..31
        const float* wp = wreg + f2 * 68;
        {
            float a0A=0.f,a1A=0.f,a2A=0.f,a3A=0.f,a4A=0.f,a5A=0.f;
            float a0B=0.f,a1B=0.f,a2B=0.f,a3B=0.f,a4B=0.f,a5B=0.f;
            #pragma unroll 2
            for (int k4 = 0; k4 < 8; ++k4) {
                const float4 wA = *(const float4*)(wp + k4 * 8);
                const float4 wB = *(const float4*)(wp + k4 * 8 + 4);
                float4 v;
                v = *(const float4*)(src + (sl       ) * 36 + 4 * k4);
                a0A += v.x*wA.x + v.y*wA.y + v.z*wA.z + v.w*wA.w;
                a0B += v.x*wB.x + v.y*wB.y + v.z*wB.z + v.w*wB.w;
                v = *(const float4*)(src + (sl + 32  ) * 36 + 4 * k4);
                a1A += v.x*wA.x + v.y*wA.y + v.z*wA.z + v.w*wA.w;
                a1B += v.x*wB.x + v.y*wB.y + v.z*wB.z + v.w*wB.w;
                v = *(const float4*)(src + (sl + 64  ) * 36 + 4 * k4);
                a2A += v.x*wA.x + v.y*wA.y + v.z*wA.z + v.w*wA.w;
                a2B += v.x*wB.x + v.y*wB.y + v.z*wB.z + v.w*wB.w;
                v = *(const float4*)(src + (sl + 96  ) * 36 + 4 * k4);
                a3A += v.x*wA.x + v.y*wA.y + v.z*wA.z + v.w*wA.w;
                a3B += v.x*wB.x + v.y*wB.y + v.z*wB.z + v.w*wB.w;
                v = *(const float4*)(src + (sl + 128 ) * 36 + 4 * k4);
                a4A += v.x*wA.x + v.y*wA.y + v.z*wA.z + v.w*wA.w;
                a4B += v.x*wB.x + v.y*wB.y + v.z*wB.z + v.w*wB.w;
                v = *(const float4*)(src + (sl + 160 ) * 36 + 4 * k4);
                a5A += v.x*wA.x + v.y*wA.y + v.z*wA.z + v.w*wA.w;
                a5B += v.x*wB.x + v.y*wB.y + v.z*wB.z + v.w*wB.w;
            }
            const int c0 = 2 * f2;
            *(float2*)(bufX + (sl       ) * 36 + c0) = make_float2(dinv[sl      ] * a0A, dinv[sl      ] * a0B);
            *(float2*)(bufX + (sl + 32  ) * 36 + c0) = make_float2(dinv[sl + 32 ] * a1A, dinv[sl + 32 ] * a1B);
            *(float2*)(bufX + (sl + 64  ) * 36 + c0) = make_float2(dinv[sl + 64 ] * a2A, dinv[sl + 64 ] * a2B);
            *(float2*)(bufX + (sl + 96  ) * 36 + c0) = make_float2(dinv[sl + 96 ] * a3A, dinv[sl + 96 ] * a3B);
            *(float2*)(bufX + (sl + 128 ) * 36 + c0) = make_float2(dinv[sl + 128] * a4A, dinv[sl + 128] * a4B);
            *(float2*)(bufX + (sl + 160 ) * 36 + c0) = make_float2(dinv[sl + 160] * a5A, dinv[sl + 160] * a5B);
        }
        if (sl < 8) {   // rows 192..199
            const int r = 192 + sl;
            float aA = 0.f, aB = 0.f;
            #pragma unroll 2
            for (int k4 = 0; k4 < 8; ++k4) {
                const float4 wA = *(const float4*)(wp + k4 * 8);
                const float4 wB = *(const float4*)(wp + k4 * 8 + 4);
                const float4 v = *(const float4*)(src + r * 36 + 4 * k4);
                aA += v.x*wA.x + v.y*wA.y + v.z*wA.z + v.w*wA.w;
                aB += v.x*wB.x + v.y*wB.y + v.z*wB.z + v.w*wB.w;
            }
            *(float2*)(bufX + r * 36 + 2 * f2) = make_float2(dinv[r] * aA, dinv[r] * aB);
        }
    };

    // paired-W staging: wreg[f2*68 + k4*8 + c*4 + j] = W[(4k4+j)*32 + 2f2+c]
    auto stage_w_paired = [&](const float* __restrict__ W) {
        for (int idx = t; idx < 1024; idx += TPB) {
            const int k = idx >> 5, f = idx & 31;
            wreg[(f >> 1) * 68 + (k >> 2) * 8 + ((f & 1) << 2) + (k & 3)] = W[idx];
        }
    };

    // ---------------- Layer 1 agg (+ stage W2/b2 in-phase, bias double-buffer) --------
    agg_layer(0, 0);    // h1 -> arch[:,0:32)
    stage_w_paired(W2);
    if (t < 32) bias[32 + t] = b2[t];
    __syncthreads();

    // ---------------- Layer 2 ----------------
    gemm_mid(hcur);
    __syncthreads();
    agg_layer(32, 32);  // h2 -> arch[:,32:64)
    stage_w_paired(W3);
    if (t < 32) bias[t] = b3[t];
    __syncthreads();

    // ---------------- Layer 3 ----------------
    gemm_mid(hcur);
    __syncthreads();
    agg_layer(-1, 0);   // h3 stays in hcur (f32), not archived
    __syncthreads();

    // conv weight staging targets (bufX dead after agg3 barrier)
    float* topv = bufX;           // [30][100] = 3000 floats
    float* cw   = bufX + 3008;    // cW1: [0,1552)  cW2 stride-81: [1552,5695); ends 7151 <= 7236

    // ---------------- Layer 4 (Fout=1): scl = dinv * (h3 @ W4); scl[200]=0 ----------------
    // Idle threads 256..511 stage cW1; threads 208..255 stage conv biases.
    float* scl = (float*)(smem + OFF_CNT);   // 400 floats available (cnt+cur dead)
    if (t < MG) {
        float a = 0.f;
        #pragma unroll 8
        for (int k = 0; k < 32; ++k) a += hcur[t * 36 + k] * W4[k];
        scl[t] = dinv[t] * a;
    }
    if (t == 200) scl[200] = 0.f;
    if (t >= 256) {
        for (int idx = t - 256; idx < 1552; idx += 256) cw[idx] = cW1[idx];
    } else if (t >= 208 && t < 224) {
        bias[t - 208] = cb1[t - 208];
    } else if (t >= 224 && t < 256) {
        bias[16 + (t - 224)] = cb2[t - 224];
    }
    __syncthreads();
    // h4k gather; idle threads stage cW2 at stride 81 (odd -> no bank aliasing in conv2)
    if (t < MG) {
        const int p0 = roff[t], p1 = roff[t + 1];
        float s = 0.f;
        for (int p = p0; p < p1; p += 4) {
            const unsigned q = *(const unsigned*)(csr + p);
            s += scl[q & 255u] + scl[(q >> 8) & 255u]
               + scl[(q >> 16) & 255u] + scl[q >> 24];
        }
        h4k[t] = fast_tanh(dinv[t] * s + b4[0]);
    }
    if (t >= 256) {
        for (int idx = t - 256; idx < 2560; idx += 256) {
            const int o = idx / 80, r = idx - o * 80;
            cw[1552 + o * 81 + r] = cW2[idx];
        }
    }
    __syncthreads();

    // ---------------- SortPool: fused exact stable rank + ord scatter ----------------
    // (desc value, asc index). Each of 200 threads ranks itself over all 200
    // (same-address LDS reads broadcast -> free); scatter ord directly.
    if (t < MG) {
        const float vi = h4k[t];
        int r = 0;
        for (int j = 0; j < MG; ++j) {
            const float vj = h4k[j];
            r += (vj > vi || (vj == vi && j < t)) ? 1 : 0;
        }
        if (r < 30) ord[r] = t;
    }
    __syncthreads();

    // ---------------- Gather top-30 features ----------
    for (int idx = t; idx < 2910; idx += TPB) {   // 30*97 grid-stride
        const int kk = idx / 97;
        const int ff = idx - kk * 97;
        const int nd = ord[kk];
        float v;
        if      (ff < 64) v = __half2float(arch[(size_t)(gbase + nd) * 64 + ff]);
        else if (ff < 96) v = hcur[nd * 36 + (ff - 64)];   // h3, f32
        else              v = h4k[nd];
        topv[kk * 100 + ff] = v;
    }
    __syncthreads();

    // conv scratch in hcur (dead after gather barrier)
    float* c1p2 = hcur;           // [16][30]
    float* c1pl = hcur + 480;     // [16][16]
    float* flat = hcur + 736;     // [352]
    float* hlin = hcur + 1088;    // [128]

    // ---------------- Conv1 (97->16 per slot) + ReLU ----------------
    if (t < 480) {
        const int o  = t & 15;
        const int tt = t >> 4;
        float a = bias[o];
        const float* wrow = cw + o * 97;
        const float* trow = topv + tt * 100;
        #pragma unroll 4
        for (int f = 0; f < 97; ++f) a += wrow[f] * trow[f];
        c1p2[o * 30 + tt] = fmaxf(a, 0.f);
    }
    __syncthreads();

    // ---------------- MaxPool1d(2,2): 30 -> 15 ----------------
    if (t < 240) {
        const int o  = t & 15;
        const int tp = t >> 4;
        c1pl[o * 16 + tp] = fmaxf(c1p2[o * 30 + 2 * tp], c1p2[o * 30 + 2 * tp + 1]);
    }
    __syncthreads();

    // ---------------- Conv2 (16->32, k=5) + ReLU -> flat; init hlin ----------------
    if (t < 352) {
        const int o  = t & 31;
        const int tt = t >> 5;
        float a = bias[16 + o];
        const float* w2r = cw + 1552 + o * 81;
        #pragma unroll
        for (int i2 = 0; i2 < 16; ++i2) {
            #pragma unroll
            for (int kk = 0; kk < 5; ++kk)
                a += w2r[i2 * 5 + kk] * c1pl[i2 * 16 + tt + kk];
        }
        flat[o * 11 + tt] = fmaxf(a, 0.f);
    } else if (t >= 352 && t < 480) {
        hlin[t - 352] = lb1[t - 352];
    }
    __syncthreads();

    // ---------------- Linear 352->128 (split-K over 4 groups of 88) ----------------
    {
        const int f  = t & 127;
        const int kc = t >> 7;   // 0..3
        float a = 0.f;
        const int k0 = kc * 88;
        #pragma unroll 4
        for (int kk = k0; kk < k0 + 88; ++kk) a += flat[kk] * lW1[kk * 128 + f];
        atomicAdd(&hlin[f], a);
    }
    __syncthreads();

    // ---------------- ReLU -> Linear 128->1 -> sigmoid ----------------
    if (t < 128) {
        float p = fmaxf(hlin[t], 0.f) * lW2[t];
        #pragma unroll
        for (int off = 32; off > 0; off >>= 1) p += __shfl_down(p, off);
        if ((t & 63) == 0) red[t >> 6] = p;
    }
    __syncthreads();
    if (t == 0) {
        const float z = red[0] + red[1] + lb2[0];
        out[g] = 1.f / (1.f + expf(-z));
    }
}

extern "C" void kernel_launch(void* const* d_in, const int* in_sizes, int n_in,
                              void* d_out, int out_size, void* d_ws, size_t ws_size,
                              hipStream_t stream) {
    (void)in_sizes; (void)n_in; (void)out_size; (void)ws_size;
    const float* x   = (const float*)d_in[0];
    const int*   ei  = (const int*)d_in[1];
    const float* W1  = (const float*)d_in[3];  const float* b1  = (const float*)d_in[4];
    const float* W2  = (const float*)d_in[5];  const float* b2  = (const float*)d_in[6];
    const float* W3  = (const float*)d_in[7];  const float* b3  = (const float*)d_in[8];
    const float* W4  = (const float*)d_in[9];  const float* b4  = (const float*)d_in[10];
    const float* cW1 = (const float*)d_in[11]; const float* cb1 = (const float*)d_in[12];
    const float* cW2 = (const float*)d_in[13]; const float* cb2 = (const float*)d_in[14];
    const float* lW1 = (const float*)d_in[15]; const float* lb1 = (const float*)d_in[16];
    const float* lW2 = (const float*)d_in[17]; const float* lb2 = (const float*)d_in[18];
    float* out = (float*)d_out;
    __half* arch = (__half*)d_ws;   // needs 512*200*64*2 = 13.1 MB

    hipFuncSetAttribute((const void*)dgcnn_kernel,
                        hipFuncAttributeMaxDynamicSharedMemorySize, SMEM_BYTES);

    dgcnn_kernel<<<GRID, TPB, SMEM_BYTES, stream>>>(
        x, ei, W1, b1, W2, b2, W3, b3, W4, b4,
        cW1, cb1, cW2, cb2, lW1, lb1, lW2, lb2, arch, out);
}

// Round 8
// 235.148 us; speedup vs baseline: 1.1431x; 1.0294x over previous
//
#include <hip/hip_runtime.h>
#include <hip/hip_fp16.h>

// DGCNN forward, fully fused: one workgroup per graph, TPB=512 (8 waves),
// 2 blocks/CU co-resident. f32 on the entire sort-key chain; h1/h2 archived
// to global f16 (conv features only); h3 read back from LDS f32.
//
// Operating point locked by R3-R17 (MI355X):
//  * TPB=512, VGPR<=60: ONLY config where 2 blocks co-reside (R15: 768/56 ->
//    1 block; R16: 640/68 -> 1 block; R13: VGPR 68 -> 1 block). 16 waves/CU cap.
//  * NO launch_bounds min-waves hints -> allocator over-shrinks.
//  * R17 FAILED: row-per-lane Phase B (8x L1/L2 x re-read) -> slower; R4's
//    broadcast-load Phase B is VALU-bound, not latency-bound, at 16 waves.
//  * R14 lesson: agg is ~LDS-port/latency bound; assignment balancing beyond
//    R2's counting sort is neutral. R2 structure = measured best (129.6us).
//  * R18 (this): R2-exact structure + (a) 2-way split cnt atomics (parity) --
//    halves same-bin/bank collisions in Phase B counting; (b) 8B packed arch
//    stores (one uint2 vs two half2) in agg finish.

#define TPB   512
#define GRID  512
#define MG    200
#define EPG   6400
#define EE    (512 * EPG)

// ---- LDS layout (byte offsets). Total 76,288 B -> 2 blocks/CU (152.6/160 KiB) ----
#define OFF_BUFX 0        // f32[201*36] rows 0..200 (row 200 = zeros); later topv[30][100] + conv W
#define OFF_HCUR 28944    // f32[200*36] h of current layer; Phase A/B: staged W1^T [32][132]
#define OFF_CSR  57744    // u8[7200]    CSR (rows padded to x4 entries, pad -> 200)
#define OFF_ROFF 64944    // i32[201] row offsets (padded units)
#define OFF_CNT  65760    // i32[200] degree counts   \ scl f32[201] aliases CNT..CUR
#define OFF_CUR  66560    // i32[200] cursors         /
#define OFF_DINV 67360    // f32[200]
#define OFF_H4   68160    // f32[200] sort key
#define OFF_RANK 68960    // i32[200]
#define OFF_ORD  69760    // i32[30]
#define OFF_BIAS 69880    // f32[64]  double-buffered layer bias
#define OFF_RED  70136    // f32[16] (+8 pad)
#define OFF_WREG 70208    // f32[1088] W2/W3 paired stage [16][8][2][4] stride 68
#define OFF_HIST 74560    // i32[32]  quad-count histogram -> offsets
#define OFF_PERM 74688    // i32[200] degree-sorted row permutation (desc)
#define OFF_CNT2 75488    // i32[200] second degree-count array (atomic split)
#define SMEM_BYTES 76288

#define QPAD 0xC8C8C8C8u   // 4x index 200 (zero row) - exact no-op quad

__device__ __forceinline__ float fast_tanh(float x) {
    const float e = __expf(2.0f * x);
    return 1.0f - 2.0f / (e + 1.0f);
}

__global__ __launch_bounds__(TPB)
void dgcnn_kernel(
    const float* __restrict__ x,
    const int*   __restrict__ ei,
    const float* __restrict__ W1, const float* __restrict__ b1,
    const float* __restrict__ W2, const float* __restrict__ b2,
    const float* __restrict__ W3, const float* __restrict__ b3,
    const float* __restrict__ W4, const float* __restrict__ b4,
    const float* __restrict__ cW1, const float* __restrict__ cb1,
    const float* __restrict__ cW2, const float* __restrict__ cb2,
    const float* __restrict__ lW1, const float* __restrict__ lb1,
    const float* __restrict__ lW2, const float* __restrict__ lb2,
    __half* __restrict__ arch,     // [512][200][64] f16 archive of h1|h2
    float* __restrict__ out)
{
    extern __shared__ unsigned char smem[];
    float* bufX = (float*)(smem + OFF_BUFX);
    float* hcur = (float*)(smem + OFF_HCUR);
    unsigned char* csr = (unsigned char*)(smem + OFF_CSR);
    int*   roff = (int*)(smem + OFF_ROFF);
    int*   cnt  = (int*)(smem + OFF_CNT);
    int*   cur  = (int*)(smem + OFF_CUR);
    float* dinv = (float*)(smem + OFF_DINV);
    float* h4k  = (float*)(smem + OFF_H4);
    int*   rank = (int*)(smem + OFF_RANK);
    int*   ord  = (int*)(smem + OFF_ORD);
    float* bias = (float*)(smem + OFF_BIAS);
    float* red  = (float*)(smem + OFF_RED);
    float* wreg = (float*)(smem + OFF_WREG);
    int*   hist = (int*)(smem + OFF_HIST);
    int*   perm = (int*)(smem + OFF_PERM);
    int*   cnt2 = (int*)(smem + OFF_CNT2);

    const int g = blockIdx.x;
    const int t = threadIdx.x;
    const int gbase = g * MG;
    const float* xg   = x + (size_t)gbase * 128;
    const int*   srcp = ei + (size_t)g * EPG;
    const int*   dstp = ei + (size_t)EE + (size_t)g * EPG;

    // ---------------- Phase A: stage W1^T -> hcur [32][132] (stride 132 == 4 mod 32),
    // csr memset to QPAD (kills pad-fill phase), bias, zeros, hist=0. ----
    for (int idx = t; idx < 4096; idx += TPB)
        hcur[(idx & 31) * 132 + (idx >> 5)] = W1[idx];
    for (int idx = t; idx < 1800; idx += TPB)
        ((unsigned*)csr)[idx] = QPAD;
    if (t < 32) bias[t] = b1[t];
    if (t < MG) { cnt[t] = 0; rank[t] = 0; }
    if (t >= 292 && t < 492) cnt2[t - 292] = 0;
    if (t >= 480) hist[t - 480] = 0;
    if (t >= 256 && t < 292) bufX[200 * 36 + (t - 256)] = 0.f;   // zero row 200
    __syncthreads();

    const int f32lane = t & 31;   // feature (output col) 0..31
    const int islot   = t >> 5;   // row slot 0..15

    // ---------------- Phase B: edge in-degree count (int4, 2-way split atomics)
    // + L1 GEMM, one phase. GEMM writes UNSCALED xw (dinv applied in Phase E -
    // identical arithmetic). W1^T read from LDS (hcur) as b128.
    {
        const int4* d4p = (const int4*)dstp;
        int* cb = (t & 1) ? cnt2 : cnt;   // e4 parity == t parity (stride TPB even)
        for (int e4 = t; e4 < EPG / 4; e4 += TPB) {
            const int4 d4 = d4p[e4];
            atomicAdd(&cb[d4.x - gbase], 1);
            atomicAdd(&cb[d4.y - gbase], 1);
            atomicAdd(&cb[d4.z - gbase], 1);
            atomicAdd(&cb[d4.w - gbase], 1);
        }
    }
    {
        const int f = f32lane;
        const float* wt = hcur + f * 132;      // column f of W1, k-major
        const float4* xv = (const float4*)xg;
        #pragma unroll
        for (int j0 = 0; j0 < 12; j0 += 6) {
            const int r0 = islot + 16 * j0;
            float a0 = 0.f, a1 = 0.f, a2 = 0.f, a3 = 0.f, a4 = 0.f, a5 = 0.f;
            #pragma unroll 2
            for (int k4 = 0; k4 < 32; ++k4) {
                const float4 w = *(const float4*)(wt + 4 * k4);
                float4 v;
                v = xv[(r0      ) * 32 + k4]; a0 += v.x*w.x + v.y*w.y + v.z*w.z + v.w*w.w;
                v = xv[(r0 + 16 ) * 32 + k4]; a1 += v.x*w.x + v.y*w.y + v.z*w.z + v.w*w.w;
                v = xv[(r0 + 32 ) * 32 + k4]; a2 += v.x*w.x + v.y*w.y + v.z*w.z + v.w*w.w;
                v = xv[(r0 + 48 ) * 32 + k4]; a3 += v.x*w.x + v.y*w.y + v.z*w.z + v.w*w.w;
                v = xv[(r0 + 64 ) * 32 + k4]; a4 += v.x*w.x + v.y*w.y + v.z*w.z + v.w*w.w;
                v = xv[(r0 + 80 ) * 32 + k4]; a5 += v.x*w.x + v.y*w.y + v.z*w.z + v.w*w.w;
            }
            bufX[(r0      ) * 36 + f] = a0;
            bufX[(r0 + 16 ) * 36 + f] = a1;
            bufX[(r0 + 32 ) * 36 + f] = a2;
            bufX[(r0 + 48 ) * 36 + f] = a3;
            bufX[(r0 + 64 ) * 36 + f] = a4;
            bufX[(r0 + 80 ) * 36 + f] = a5;
        }
        if (islot < 8) {   // rows 192..199
            const int r = 192 + islot;
            float a0 = 0.f;
            #pragma unroll 2
            for (int k4 = 0; k4 < 32; ++k4) {
                const float4 w = *(const float4*)(wt + 4 * k4);
                const float4 v = xv[r * 32 + k4];
                a0 += v.x*w.x + v.y*w.y + v.z*w.z + v.w*w.w;
            }
            bufX[r * 36 + f] = a0;
        }
    }
    __syncthreads();

    // ---------------- Phase C: dinv + hist build + prefix scan over PADDED row lengths ----
    if (t >= 256 && t < 256 + MG) {
        const int i = t - 256;
        const int c = cnt[i] + cnt2[i];
        dinv[i] = 1.0f / sqrtf((float)(c + 1));
        int qc = (c + 4) >> 2;                 // padded quad count
        if (qc > 31) qc = 31;
        atomicAdd(&hist[31 - qc], 1);          // descending order
    }
    if (t < 64) {
        if (t == 0) roff[0] = 0;
        int carry = 0;
        #pragma unroll
        for (int c = 0; c < 4; ++c) {
            const int i = c * 64 + t;
            int v = (i < MG) ? ((cnt[i] + cnt2[i] + 4) & ~3) : 0;   // self-loop +1, pad x4
            #pragma unroll
            for (int off = 1; off < 64; off <<= 1) {
                int u = __shfl_up(v, off);
                if (t >= (int)off) v += u;
            }
            if (i < MG) roff[i + 1] = carry + v;
            carry += __shfl(v, 63);
        }
    }
    __syncthreads();

    // ---------------- Phase D: self-loop entry + cursors + hist exclusive prefix ----------
    if (t < MG) {
        int p = roff[t];
        csr[p] = (unsigned char)t;
        cur[t] = p + 1;
    }
    if (t < 32) {
        const int own = hist[t];
        int v = own;
        #pragma unroll
        for (int off = 1; off < 32; off <<= 1) {
            int u = __shfl_up(v, off);
            if (t >= off) v += u;
        }
        hist[t] = v - own;   // exclusive offsets
    }
    __syncthreads();

    // ---------------- Phase E: CSR placement + dinv-scale bufX + perm scatter ------------
    {
        const int4* s4p = (const int4*)srcp;
        const int4* d4p = (const int4*)dstp;
        for (int e4 = t; e4 < EPG / 4; e4 += TPB) {
            const int4 s4 = s4p[e4];
            const int4 d4 = d4p[e4];
            int p;
            p = atomicAdd(&cur[d4.x - gbase], 1); csr[p] = (unsigned char)(s4.x - gbase);
            p = atomicAdd(&cur[d4.y - gbase], 1); csr[p] = (unsigned char)(s4.y - gbase);
            p = atomicAdd(&cur[d4.z - gbase], 1); csr[p] = (unsigned char)(s4.z - gbase);
            p = atomicAdd(&cur[d4.w - gbase], 1); csr[p] = (unsigned char)(s4.w - gbase);
        }
    }
    for (int r = islot; r < MG; r += 16) {
        bufX[r * 36 + f32lane] *= dinv[r];
    }
    if (t < MG) {
        int qc = (cnt[t] + cnt2[t] + 4) >> 2;
        if (qc > 31) qc = 31;
        const int pos = atomicAdd(&hist[31 - qc], 1);
        perm[pos] = t;   // perm: rows sorted by quad count, descending
    }
    __syncthreads();

    // agg: hcur[d][f] = tanh(dinv[d]*sum_{p} bufX[csr[p]][f] + bias[bb+f]);
    // 2-row interleaved + csr-quad prefetch, rows assigned via degree-sorted perm
    // so each wave's 16 rows have similar quad counts (lockstep max ~= mean).
    auto agg_layer = [&](int archOff, int bb) {
        const int f4  = (t & 7) << 2;
        const int dsl = t >> 3;   // 0..63

        auto finish = [&](int d, float a0, float a1, float a2, float a3) {
            const float dv = dinv[d];
            const float o0 = fast_tanh(dv * a0 + bias[bb + f4 + 0]);
            const float o1 = fast_tanh(dv * a1 + bias[bb + f4 + 1]);
            const float o2 = fast_tanh(dv * a2 + bias[bb + f4 + 2]);
            const float o3 = fast_tanh(dv * a3 + bias[bb + f4 + 3]);
            *(float4*)(hcur + d * 36 + f4) = make_float4(o0, o1, o2, o3);
            if (archOff >= 0) {
                const __half2 p01 = __floats2half2_rn(o0, o1);
                const __half2 p23 = __floats2half2_rn(o2, o3);
                uint2 pk;
                pk.x = *(const unsigned*)&p01;
                pk.y = *(const unsigned*)&p23;
                *(uint2*)(arch + (size_t)(gbase + d) * 64 + archOff + f4) = pk;
            }
        };

        auto pair_rows = [&](int da, int db) {
            const int p1a = roff[da + 1], p1b = roff[db + 1];
            int pa = roff[da], pb = roff[db];
            const int na = (p1a - pa) >> 2, nb = (p1b - pb) >> 2;
            const int iters = na > nb ? na : nb;
            unsigned qa = *(const unsigned*)(csr + pa);
            unsigned qb = *(const unsigned*)(csr + pb);
            float a0=0.f,a1=0.f,a2=0.f,a3=0.f, c0=0.f,c1=0.f,c2=0.f,c3=0.f;
            for (int i = 0; i < iters; ++i) {
                pa += 4; pb += 4;
                const unsigned qa_n = (pa < p1a) ? *(const unsigned*)(csr + pa) : QPAD;
                const unsigned qb_n = (pb < p1b) ? *(const unsigned*)(csr + pb) : QPAD;
                float4 v;
                v = *(const float4*)(bufX + (qa & 255u) * 36 + f4);         a0+=v.x; a1+=v.y; a2+=v.z; a3+=v.w;
                v = *(const float4*)(bufX + ((qa >> 8) & 255u) * 36 + f4);  a0+=v.x; a1+=v.y; a2+=v.z; a3+=v.w;
                v = *(const float4*)(bufX + ((qa >> 16) & 255u) * 36 + f4); a0+=v.x; a1+=v.y; a2+=v.z; a3+=v.w;
                v = *(const float4*)(bufX + (qa >> 24) * 36 + f4);          a0+=v.x; a1+=v.y; a2+=v.z; a3+=v.w;
                v = *(const float4*)(bufX + (qb & 255u) * 36 + f4);         c0+=v.x; c1+=v.y; c2+=v.z; c3+=v.w;
                v = *(const float4*)(bufX + ((qb >> 8) & 255u) * 36 + f4);  c0+=v.x; c1+=v.y; c2+=v.z; c3+=v.w;
                v = *(const float4*)(bufX + ((qb >> 16) & 255u) * 36 + f4); c0+=v.x; c1+=v.y; c2+=v.z; c3+=v.w;
                v = *(const float4*)(bufX + (qb >> 24) * 36 + f4);          c0+=v.x; c1+=v.y; c2+=v.z; c3+=v.w;
                qa = qa_n; qb = qb_n;
            }
            finish(da, a0, a1, a2, a3);
            finish(db, c0, c1, c2, c3);
        };

        auto one_row = [&](int d) {
            const int p1 = roff[d + 1];
            int p = roff[d];
            const int iters = (p1 - p) >> 2;
            unsigned q = *(const unsigned*)(csr + p);
            float a0=0.f,a1=0.f,a2=0.f,a3=0.f;
            for (int i = 0; i < iters; ++i) {
                p += 4;
                const unsigned q_n = (p < p1) ? *(const unsigned*)(csr + p) : QPAD;
                float4 v;
                v = *(const float4*)(bufX + (q & 255u) * 36 + f4);         a0+=v.x; a1+=v.y; a2+=v.z; a3+=v.w;
                v = *(const float4*)(bufX + ((q >> 8) & 255u) * 36 + f4);  a0+=v.x; a1+=v.y; a2+=v.z; a3+=v.w;
                v = *(const float4*)(bufX + ((q >> 16) & 255u) * 36 + f4); a0+=v.x; a1+=v.y; a2+=v.z; a3+=v.w;
                v = *(const float4*)(bufX + (q >> 24) * 36 + f4);          a0+=v.x; a1+=v.y; a2+=v.z; a3+=v.w;
                q = q_n;
            }
            finish(d, a0, a1, a2, a3);
        };

        // Pass 1: rows perm[2g], perm[2g+1] (sorted-adjacent pairs, ranks 0..127).
        // Pass 2: ranks 128..199. Wave 0 (dsl 0..7) pair path (128..135 x 192..199);
        // waves 1..7 singles 136..191 -> no intra-wave divergence.
        pair_rows(perm[2 * dsl], perm[2 * dsl + 1]);
        if (dsl < 8) pair_rows(perm[128 + dsl], perm[192 + dsl]);
        else         one_row(perm[128 + dsl]);
    };

    auto gemm_mid = [&](const float* __restrict__ src) {
        // bufX = (src[200x32] @ W[32x32]) scaled by dinv[row]; W staged paired in
        // wreg: [f2][k4][c][4] stride 68 (== 4 mod 32, 2-way banks). Col-pair x
        // 6-row mapping: each src b128 feeds 8 FMAs (halves activation reads).
        const int f2 = t & 15;    // column pair: cols 2*f2, 2*f2+1
        const int sl = t >> 4;    // row slot 0..31
        const float* wp = wreg + f2 * 68;
        {
            float a0A=0.f,a1A=0.f,a2A=0.f,a3A=0.f,a4A=0.f,a5A=0.f;
            float a0B=0.f,a1B=0.f,a2B=0.f,a3B=0.f,a4B=0.f,a5B=0.f;
            #pragma unroll 2
            for (int k4 = 0; k4 < 8; ++k4) {
                const float4 wA = *(const float4*)(wp + k4 * 8);
                const float4 wB = *(const float4*)(wp + k4 * 8 + 4);
                float4 v;
                v = *(const float4*)(src + (sl       ) * 36 + 4 * k4);
                a0A += v.x*wA.x + v.y*wA.y + v.z*wA.z + v.w*wA.w;
                a0B += v.x*wB.x + v.y*wB.y + v.z*wB.z + v.w*wB.w;
                v = *(const float4*)(src + (sl + 32  ) * 36 + 4 * k4);
                a1A += v.x*wA.x + v.y*wA.y + v.z*wA.z + v.w*wA.w;
                a1B += v.x*wB.x + v.y*wB.y + v.z*wB.z + v.w*wB.w;
                v = *(const float4*)(src + (sl + 64  ) * 36 + 4 * k4);
                a2A += v.x*wA.x + v.y*wA.y + v.z*wA.z + v.w*wA.w;
                a2B += v.x*wB.x + v.y*wB.y + v.z*wB.z + v.w*wB.w;
                v = *(const float4*)(src + (sl + 96  ) * 36 + 4 * k4);
                a3A += v.x*wA.x + v.y*wA.y + v.z*wA.z + v.w*wA.w;
                a3B += v.x*wB.x + v.y*wB.y + v.z*wB.z + v.w*wB.w;
                v = *(const float4*)(src + (sl + 128 ) * 36 + 4 * k4);
                a4A += v.x*wA.x + v.y*wA.y + v.z*wA.z + v.w*wA.w;
                a4B += v.x*wB.x + v.y*wB.y + v.z*wB.z + v.w*wB.w;
                v = *(const float4*)(src + (sl + 160 ) * 36 + 4 * k4);
                a5A += v.x*wA.x + v.y*wA.y + v.z*wA.z + v.w*wA.w;
                a5B += v.x*wB.x + v.y*wB.y + v.z*wB.z + v.w*wB.w;
            }
            const int c0 = 2 * f2;
            *(float2*)(bufX + (sl       ) * 36 + c0) = make_float2(dinv[sl      ] * a0A, dinv[sl      ] * a0B);
            *(float2*)(bufX + (sl + 32  ) * 36 + c0) = make_float2(dinv[sl + 32 ] * a1A, dinv[sl + 32 ] * a1B);
            *(float2*)(bufX + (sl + 64  ) * 36 + c0) = make_float2(dinv[sl + 64 ] * a2A, dinv[sl + 64 ] * a2B);
            *(float2*)(bufX + (sl + 96  ) * 36 + c0) = make_float2(dinv[sl + 96 ] * a3A, dinv[sl + 96 ] * a3B);
            *(float2*)(bufX + (sl + 128 ) * 36 + c0) = make_float2(dinv[sl + 128] * a4A, dinv[sl + 128] * a4B);
            *(float2*)(bufX + (sl + 160 ) * 36 + c0) = make_float2(dinv[sl + 160] * a5A, dinv[sl + 160] * a5B);
        }
        if (sl < 8) {   // rows 192..199
            const int r = 192 + sl;
            float aA = 0.f, aB = 0.f;
            #pragma unroll 2
            for (int k4 = 0; k4 < 8; ++k4) {
                const float4 wA = *(const float4*)(wp + k4 * 8);
                const float4 wB = *(const float4*)(wp + k4 * 8 + 4);
                const float4 v = *(const float4*)(src + r * 36 + 4 * k4);
                aA += v.x*wA.x + v.y*wA.y + v.z*wA.z + v.w*wA.w;
                aB += v.x*wB.x + v.y*wB.y + v.z*wB.z + v.w*wB.w;
            }
            *(float2*)(bufX + r * 36 + 2 * f2) = make_float2(dinv[r] * aA, dinv[r] * aB);
        }
    };

    // paired-W staging: wreg[f2*68 + k4*8 + c*4 + j] = W[(4k4+j)*32 + 2f2+c]
    auto stage_w_paired = [&](const float* __restrict__ W) {
        for (int idx = t; idx < 1024; idx += TPB) {
            const int k = idx >> 5, f = idx & 31;
            wreg[(f >> 1) * 68 + (k >> 2) * 8 + ((f & 1) << 2) + (k & 3)] = W[idx];
        }
    };

    // ---------------- Layer 1 agg (+ stage W2/b2 in-phase, bias double-buffer) --------
    agg_layer(0, 0);    // h1 -> arch[:,0:32)
    stage_w_paired(W2);
    if (t < 32) bias[32 + t] = b2[t];
    __syncthreads();

    // ---------------- Layer 2 ----------------
    gemm_mid(hcur);
    __syncthreads();
    agg_layer(32, 32);  // h2 -> arch[:,32:64)
    stage_w_paired(W3);
    if (t < 32) bias[t] = b3[t];
    __syncthreads();

    // ---------------- Layer 3 ----------------
    gemm_mid(hcur);
    __syncthreads();
    agg_layer(-1, 0);   // h3 stays in hcur (f32), not archived
    __syncthreads();

    // conv weight staging targets (bufX dead after agg3 barrier)
    float* topv = bufX;           // [30][100] = 3000 floats
    float* cw   = bufX + 3008;    // cW1: [0,1552)  cW2 stride-81: [1552,5695); ends 7151 <= 7236

    // ---------------- Layer 4 (Fout=1): scl = dinv * (h3 @ W4); scl[200]=0 ----------------
    // Idle threads 256..511 stage cW1; threads 208..255 stage conv biases.
    float* scl = (float*)(smem + OFF_CNT);   // 400 floats available (cnt+cur dead)
    if (t < MG) {
        float a = 0.f;
        #pragma unroll 8
        for (int k = 0; k < 32; ++k) a += hcur[t * 36 + k] * W4[k];
        scl[t] = dinv[t] * a;
    }
    if (t == 200) scl[200] = 0.f;
    if (t >= 256) {
        for (int idx = t - 256; idx < 1552; idx += 256) cw[idx] = cW1[idx];
    } else if (t >= 208 && t < 224) {
        bias[t - 208] = cb1[t - 208];
    } else if (t >= 224 && t < 256) {
        bias[16 + (t - 224)] = cb2[t - 224];
    }
    __syncthreads();
    // h4k gather; idle threads stage cW2 at stride 81 (odd -> no bank aliasing in conv2)
    if (t < MG) {
        const int p0 = roff[t], p1 = roff[t + 1];
        float s = 0.f;
        for (int p = p0; p < p1; p += 4) {
            const unsigned q = *(const unsigned*)(csr + p);
            s += scl[q & 255u] + scl[(q >> 8) & 255u]
               + scl[(q >> 16) & 255u] + scl[q >> 24];
        }
        h4k[t] = fast_tanh(dinv[t] * s + b4[0]);
    }
    if (t >= 256) {
        for (int idx = t - 256; idx < 2560; idx += 256) {
            const int o = idx / 80, r = idx - o * 80;
            cw[1552 + o * 81 + r] = cW2[idx];
        }
    }
    __syncthreads();

    // ---------------- SortPool: exact stable rank (desc value, asc index) ----------------
    {
        const int i = t & 255;
        const int half = t >> 8;   // 0 or 1
        if (i < MG) {
            const float vi = h4k[i];
            int r = 0;
            const int j0 = half * 100, j1 = half * 100 + 100;
            for (int j = j0; j < j1; ++j) {
                const float vj = h4k[j];
                r += (vj > vi || (vj == vi && j < i)) ? 1 : 0;
            }
            atomicAdd(&rank[i], r);
        }
    }
    __syncthreads();
    if (t < MG) {
        const int r = rank[t];
        if (r < 30) ord[r] = t;
    }
    __syncthreads();

    // ---------------- Gather top-30 features ----------
    for (int idx = t; idx < 2910; idx += TPB) {   // 30*97 grid-stride
        const int kk = idx / 97;
        const int ff = idx - kk * 97;
        const int nd = ord[kk];
        float v;
        if      (ff < 64) v = __half2float(arch[(size_t)(gbase + nd) * 64 + ff]);
        else if (ff < 96) v = hcur[nd * 36 + (ff - 64)];   // h3, f32
        else              v = h4k[nd];
        topv[kk * 100 + ff] = v;
    }
    __syncthreads();

    // conv scratch in hcur (dead after gather barrier)
    float* c1p2 = hcur;           // [16][30]
    float* c1pl = hcur + 480;     // [16][16]
    float* flat = hcur + 736;     // [352]
    float* hlin = hcur + 1088;    // [128]

    // ---------------- Conv1 (97->16 per slot) + ReLU ----------------
    if (t < 480) {
        const int o  = t & 15;
        const int tt = t >> 4;
        float a = bias[o];
        const float* wrow = cw + o * 97;
        const float* trow = topv + tt * 100;
        #pragma unroll 4
        for (int f = 0; f < 97; ++f) a += wrow[f] * trow[f];
        c1p2[o * 30 + tt] = fmaxf(a, 0.f);
    }
    __syncthreads();

    // ---------------- MaxPool1d(2,2): 30 -> 15 ----------------
    if (t < 240) {
        const int o  = t & 15;
        const int tp = t >> 4;
        c1pl[o * 16 + tp] = fmaxf(c1p2[o * 30 + 2 * tp], c1p2[o * 30 + 2 * tp + 1]);
    }
    __syncthreads();

    // ---------------- Conv2 (16->32, k=5) + ReLU -> flat; init hlin ----------------
    if (t < 352) {
        const int o  = t & 31;
        const int tt = t >> 5;
        float a = bias[16 + o];
        const float* w2r = cw + 1552 + o * 81;
        #pragma unroll
        for (int i2 = 0; i2 < 16; ++i2) {
            #pragma unroll
            for (int kk = 0; kk < 5; ++kk)
                a += w2r[i2 * 5 + kk] * c1pl[i2 * 16 + tt + kk];
        }
        flat[o * 11 + tt] = fmaxf(a, 0.f);
    } else if (t >= 352 && t < 480) {
        hlin[t - 352] = lb1[t - 352];
    }
    __syncthreads();

    // ---------------- Linear 352->128 (split-K over 4 groups of 88) ----------------
    {
        const int f  = t & 127;
        const int kc = t >> 7;   // 0..3
        float a = 0.f;
        const int k0 = kc * 88;
        #pragma unroll 4
        for (int kk = k0; kk < k0 + 88; ++kk) a += flat[kk] * lW1[kk * 128 + f];
        atomicAdd(&hlin[f], a);
    }
    __syncthreads();

    // ---------------- ReLU -> Linear 128->1 -> sigmoid ----------------
    if (t < 128) {
        float p = fmaxf(hlin[t], 0.f) * lW2[t];
        #pragma unroll
        for (int off = 32; off > 0; off >>= 1) p += __shfl_down(p, off);
        if ((t & 63) == 0) red[t >> 6] = p;
    }
    __syncthreads();
    if (t == 0) {
        const float z = red[0] + red[1] + lb2[0];
        out[g] = 1.f / (1.f + expf(-z));
    }
}

extern "C" void kernel_launch(void* const* d_in, const int* in_sizes, int n_in,
                              void* d_out, int out_size, void* d_ws, size_t ws_size,
                              hipStream_t stream) {
    (void)in_sizes; (void)n_in; (void)out_size; (void)ws_size;
    const float* x   = (const float*)d_in[0];
    const int*   ei  = (const int*)d_in[1];
    const float* W1  = (const float*)d_in[3];  const float* b1  = (const float*)d_in[4];
    const float* W2  = (const float*)d_in[5];  const float* b2  = (const float*)d_in[6];
    const float* W3  = (const float*)d_in[7];  const float* b3  = (const float*)d_in[8];
    const float* W4  = (const float*)d_in[9];  const float* b4  = (const float*)d_in[10];
    const float* cW1 = (const float*)d_in[11]; const float* cb1 = (const float*)d_in[12];
    const float* cW2 = (const float*)d_in[13]; const float* cb2 = (const float*)d_in[14];
    const float* lW1 = (const float*)d_in[15]; const float* lb1 = (const float*)d_in[16];
    const float* lW2 = (const float*)d_in[17]; const float* lb2 = (const float*)d_in[18];
    float* out = (float*)d_out;
    __half* arch = (__half*)d_ws;   // needs 512*200*64*2 = 13.1 MB

    hipFuncSetAttribute((const void*)dgcnn_kernel,
                        hipFuncAttributeMaxDynamicSharedMemorySize, SMEM_BYTES);

    dgcnn_kernel<<<GRID, TPB, SMEM_BYTES, stream>>>(
        x, ei, W1, b1, W2, b2, W3, b3, W4, b4,
        cW1, cb1, cW2, cb2, lW1, lb1, lW2, lb2, arch, out);
}